// Round 8
// baseline (1650.821 us; speedup 1.0000x reference)
//
#include <hip/hip_runtime.h>

// ---------------- problem constants ----------------
#define D_SZ 512
#define S_SZ 1024
#define H_SZ 2048
#define BS_SZ 32768
#define H_STEP 0.1f
#define ROWS 128          // i-rows per block
#define HB 128            // h-block size
#define NHB 16            // H_SZ / HB

typedef __attribute__((ext_vector_type(4))) float f32x4;
typedef __attribute__((ext_vector_type(8))) short s16x8;
typedef __attribute__((ext_vector_type(4))) unsigned short u16x4;
typedef unsigned short ushort_t;

__device__ __forceinline__ ushort_t f2b(float f) {
    unsigned u = __float_as_uint(f);
    unsigned r = (u + 0x7FFFu + ((u >> 16) & 1u)) >> 16;
    return (ushort_t)r;
}

__device__ __forceinline__ void gload_lds16(const void* g, void* l) {
    __builtin_amdgcn_global_load_lds(
        (const __attribute__((address_space(1))) unsigned int*)g,
        (__attribute__((address_space(3))) unsigned int*)l, 16, 0, 0);
}

// ---------------- prep kernels ----------------
__global__ void prep_w1(const float* __restrict__ W1,
                        ushort_t* __restrict__ W1b,
                        ushort_t* __restrict__ W1T) {
    int idx = blockIdx.x * 256 + threadIdx.x;   // over H*D = 1M
    float v = W1[idx];
    ushort_t b = f2b(v);
    int h = idx >> 9;          // / 512
    int d = idx & 511;
    W1b[idx] = b;
    W1T[(size_t)d * H_SZ + h] = b;
}

__global__ void prep_mass(const float* __restrict__ logm,
                          float* __restrict__ inv_mass,
                          float* __restrict__ mass) {
    int s = blockIdx.x * 256 + threadIdx.x;
    if (s < S_SZ) {
        float lm = logm[s];
        mass[s] = expf(lm);
        inv_mass[s] = expf(-lm);
    }
}

// ---------------- embedding + p0 ----------------
__global__ void embed_kernel(const float* __restrict__ table,
                             const int* __restrict__ ids,
                             const float* __restrict__ mass,
                             float* __restrict__ q,
                             float* __restrict__ p,
                             ushort_t* __restrict__ qb) {
    int i = blockIdx.x;          // row index in [0, BS)
    int t = threadIdx.x;
    int s = i & (S_SZ - 1);
    int id = ids[i];
    int idp = (s == 0) ? id : ids[i - 1];   // s==0: prev = self -> vel 0
    float mk = (id != 0) ? 1.f : 0.f;
    float ms = mass[s];
    int d0 = t * 4;

    f32x4 cur = {0.f, 0.f, 0.f, 0.f};
    f32x4 prv = {0.f, 0.f, 0.f, 0.f};
    if (id != 0)  cur = *(const f32x4*)(table + (size_t)id  * D_SZ + d0);
    if (idp != 0) prv = *(const f32x4*)(table + (size_t)idp * D_SZ + d0);

    size_t off = (size_t)i * D_SZ + d0;
    *(f32x4*)(q + off) = cur;
    u16x4 cb;
    cb[0] = f2b(cur[0]); cb[1] = f2b(cur[1]); cb[2] = f2b(cur[2]); cb[3] = f2b(cur[3]);
    *(u16x4*)(qb + off) = cb;

    f32x4 pv;
    pv[0] = ms * (cur[0] - prv[0]) * mk;
    pv[1] = ms * (cur[1] - prv[1]) * mk;
    pv[2] = ms * (cur[2] - prv[2]) * mk;
    pv[3] = ms * (cur[3] - prv[3]) * mk;
    *(f32x4*)(p + off) = pv;
}

// =====================================================================
// Fused row-local leapfrog: grid 256 x 512 thr, block owns 128 rows.
// All 6 force evals + p/q updates inside; U exists only in LDS.
// Per force, per h-block (HB=128):
//   GEMM1: C1[128h][128i] = W1b_hb x qb   (K=512, both staged, 16 K-tiles)
//   sech2 epilogue -> Ub[128i][128h] (LDS, padded stride 136)
//   GEMM2: G[512d][128i] += W1T x Ub      (K=128, W1T staged, 4 K-tiles)
// Wave grid 4x2 (wg=h/d groups, wi=i groups).
//   GEMM1 wave: 32h x 64i, acc1[2][4]. GEMM2 wave: 128d x 64i, acc2[8][4].
// 2-barrier counted-vmcnt K-loops (R3-proven). T2 swizzle throughout.
// Leapfrog epilogue: p -= coef*mask*G; q += 0.1*p*im*mask; qb=bf16(q).
// p/q master in global f32 (128 MB working set -> L3-resident).
// =====================================================================
__global__ __launch_bounds__(512, 2) void leapfrog(
        const ushort_t* __restrict__ W1b,   // [2048, 512]
        const ushort_t* __restrict__ W1T,   // [512, 2048]
        const float* __restrict__ b1,
        const float* __restrict__ W2,
        const int* __restrict__ ids,
        const float* __restrict__ inv_mass,
        float* __restrict__ q,
        float* __restrict__ p,
        ushort_t* __restrict__ qb) {
    __shared__ __align__(16) ushort_t g1A[2][128 * 32];   // 16 KB  W1b tiles
    __shared__ __align__(16) ushort_t g1B[2][128 * 32];   // 16 KB  qb tiles
    __shared__ __align__(16) ushort_t g2A[2][512 * 32];   // 64 KB  W1T tiles
    __shared__ __align__(16) ushort_t Ub[128 * 136];      // 34 KB  U block (padded)

    const int tid = threadIdx.x;
    const int lane = tid & 63, wid = tid >> 6;
    const int wg = wid >> 1, wi = wid & 1;     // 4 (h/d) x 2 (i) wave grid
    const int lr = lane & 15, lk = lane >> 4;

    const long i0 = (long)blockIdx.x * ROWS;

    // staging thread mapping: chunk row r0 = tid>>2, 16B-slot kc = tid&3,
    // pre-swizzled source slot kcs = kc ^ ((r0>>1)&3)   [T2]
    const int r0  = tid >> 2;
    const int kc  = tid & 3;
    const int kcs = kc ^ ((r0 >> 1) & 3);
    const ushort_t* gqb  = qb  + (i0 + r0) * (long)D_SZ + kcs * 8;
    const ushort_t* gW1b = W1b + (long)r0 * D_SZ + kcs * 8;
    const ushort_t* gW1T = W1T + (long)r0 * H_SZ + kcs * 8;

    // ds_read swizzled k-slot (key = (lr>>1)&3, valid for 16-aligned row bases)
    const int lswz = (lk ^ ((lr >> 1) & 3)) * 8;

#define STG1(hb, kt) { \
    gload_lds16(gW1b + (long)(hb) * (128 * D_SZ) + (kt) * 32, &g1A[(kt) & 1][tid * 8]); \
    gload_lds16(gqb + (kt) * 32,                              &g1B[(kt) & 1][tid * 8]); }
#define STG2(hb, kt) { \
    gload_lds16(gW1T + (hb) * 128 + (kt) * 32,                     &g2A[(kt) & 1][tid * 8]);          \
    gload_lds16(gW1T + (long)128 * H_SZ + (hb) * 128 + (kt) * 32,  &g2A[(kt) & 1][(tid + 512) * 8]);  \
    gload_lds16(gW1T + (long)256 * H_SZ + (hb) * 128 + (kt) * 32,  &g2A[(kt) & 1][(tid + 1024) * 8]); \
    gload_lds16(gW1T + (long)384 * H_SZ + (hb) * 128 + (kt) * 32,  &g2A[(kt) & 1][(tid + 1536) * 8]); }

    #pragma unroll 1
    for (int j = 0; j < 6; ++j) {
        const float coef = (j == 0 || j == 5) ? 0.05f : 0.1f;
        const int do_q = (j < 5);

        f32x4 acc2[8][4];
        #pragma unroll
        for (int m = 0; m < 8; ++m)
            #pragma unroll
            for (int n = 0; n < 4; ++n)
                acc2[m][n] = (f32x4){0.f, 0.f, 0.f, 0.f};

        #pragma unroll 1
        for (int hb = 0; hb < NHB; ++hb) {
            // ================= GEMM1: C1[128h][128i], K=512 =================
            f32x4 acc1[2][4];
            #pragma unroll
            for (int m = 0; m < 2; ++m)
                #pragma unroll
                for (int n = 0; n < 4; ++n)
                    acc1[m][n] = (f32x4){0.f, 0.f, 0.f, 0.f};

            STG1(hb, 0);
            #pragma unroll
            for (int kt = 0; kt < 16; ++kt) {
                if (kt < 15) {
                    STG1(hb, kt + 1);
                    asm volatile("s_waitcnt vmcnt(2)" ::: "memory");
                } else {
                    asm volatile("s_waitcnt vmcnt(0)" ::: "memory");
                }
                __builtin_amdgcn_s_barrier();

                s16x8 a1[2], bf[4];
                #pragma unroll
                for (int mh = 0; mh < 2; ++mh)
                    a1[mh] = *(const s16x8*)&g1A[kt & 1][(wg * 32 + mh * 16 + lr) * 32 + lswz];
                #pragma unroll
                for (int ni = 0; ni < 4; ++ni)
                    bf[ni] = *(const s16x8*)&g1B[kt & 1][(wi * 64 + ni * 16 + lr) * 32 + lswz];
                asm volatile("s_waitcnt lgkmcnt(0)" ::: "memory");
                __builtin_amdgcn_sched_barrier(0);
                __builtin_amdgcn_s_setprio(1);
                #pragma unroll
                for (int mh = 0; mh < 2; ++mh)
                    #pragma unroll
                    for (int ni = 0; ni < 4; ++ni)
                        acc1[mh][ni] = __builtin_amdgcn_mfma_f32_16x16x32_bf16(a1[mh], bf[ni], acc1[mh][ni], 0, 0, 0);
                __builtin_amdgcn_s_setprio(0);
                __builtin_amdgcn_s_barrier();
            }

            // ---- U epilogue: Ub[i][h] = bf16(sech2(C1 + b1)*w2) ----
            #pragma unroll
            for (int mh = 0; mh < 2; ++mh) {
                int h0 = wg * 32 + mh * 16 + lk * 4;          // local h in [0,128)
                f32x4 b1v = *(const f32x4*)(b1 + hb * HB + h0);
                f32x4 w2v = *(const f32x4*)(W2 + hb * HB + h0);
                int kt32 = h0 >> 5, slot = (h0 >> 3) & 3, e = h0 & 7;
                int pbase = kt32 * 32 + ((slot ^ ((lr >> 1) & 3)) * 8) + e;
                #pragma unroll
                for (int ni = 0; ni < 4; ++ni) {
                    int i = wi * 64 + ni * 16 + lr;
                    u16x4 ub;
                    #pragma unroll
                    for (int jj = 0; jj < 4; ++jj) {
                        float uu = acc1[mh][ni][jj] + b1v[jj];
                        float e2 = __expf(-2.0f * fabsf(uu));
                        float rc = 1.0f / (1.0f + e2);
                        ub[jj] = f2b(4.0f * e2 * rc * rc * w2v[jj]);
                    }
                    *(u16x4*)&Ub[i * 136 + pbase] = ub;
                }
            }
            asm volatile("s_waitcnt lgkmcnt(0)" ::: "memory");
            __builtin_amdgcn_s_barrier();

            // ================= GEMM2: G[512d][128i] += W1T x Ub, K=128 =================
            STG2(hb, 0);
            #pragma unroll
            for (int kt = 0; kt < 4; ++kt) {
                if (kt < 3) {
                    STG2(hb, kt + 1);
                    asm volatile("s_waitcnt vmcnt(4)" ::: "memory");
                } else {
                    asm volatile("s_waitcnt vmcnt(0)" ::: "memory");
                }
                __builtin_amdgcn_s_barrier();

                s16x8 a2[8], b2[4];
                #pragma unroll
                for (int md = 0; md < 8; ++md)
                    a2[md] = *(const s16x8*)&g2A[kt & 1][(wg * 128 + md * 16 + lr) * 32 + lswz];
                #pragma unroll
                for (int ni = 0; ni < 4; ++ni)
                    b2[ni] = *(const s16x8*)&Ub[(wi * 64 + ni * 16 + lr) * 136 + kt * 32 + lswz];
                asm volatile("s_waitcnt lgkmcnt(0)" ::: "memory");
                __builtin_amdgcn_sched_barrier(0);
                __builtin_amdgcn_s_setprio(1);
                #pragma unroll
                for (int md = 0; md < 8; ++md)
                    #pragma unroll
                    for (int ni = 0; ni < 4; ++ni)
                        acc2[md][ni] = __builtin_amdgcn_mfma_f32_16x16x32_bf16(a2[md], b2[ni], acc2[md][ni], 0, 0, 0);
                __builtin_amdgcn_s_setprio(0);
                __builtin_amdgcn_s_barrier();
            }
        }

        // ================= leapfrog update =================
        #pragma unroll
        for (int ni = 0; ni < 4; ++ni) {
            long gi = i0 + wi * 64 + ni * 16 + lr;
            int id = ids[gi];
            float cm = (id != 0) ? coef : 0.f;
            float hm = (id != 0) ? H_STEP : 0.f;
            float im = inv_mass[(int)(gi & (S_SZ - 1))];
            #pragma unroll
            for (int md = 0; md < 8; ++md) {
                int d0 = wg * 128 + md * 16 + lk * 4;
                size_t off = (size_t)gi * D_SZ + d0;
                f32x4 pv = *(const f32x4*)(p + off);
                #pragma unroll
                for (int jj = 0; jj < 4; ++jj)
                    pv[jj] -= cm * acc2[md][ni][jj];
                *(f32x4*)(p + off) = pv;
                if (do_q) {
                    f32x4 qv = *(const f32x4*)(q + off);
                    u16x4 qbv;
                    #pragma unroll
                    for (int jj = 0; jj < 4; ++jj) {
                        qv[jj] += hm * pv[jj] * im;
                        qbv[jj] = f2b(qv[jj]);
                    }
                    *(f32x4*)(q + off) = qv;
                    *(u16x4*)(qb + off) = qbv;
                }
            }
        }
        // drain stores so next force's counted vmcnt staging is exact,
        // and qb stores are visible to gload_lds (L2) before re-staging.
        asm volatile("s_waitcnt vmcnt(0)" ::: "memory");
        __builtin_amdgcn_s_barrier();
    }
#undef STG1
#undef STG2
}

// ---------------- host launch ----------------
extern "C" void kernel_launch(void* const* d_in, const int* in_sizes, int n_in,
                              void* d_out, int out_size, void* d_ws, size_t ws_size,
                              hipStream_t stream) {
    const float* table = (const float*)d_in[0];
    const float* logm  = (const float*)d_in[1];
    const float* W1    = (const float*)d_in[2];
    const float* b1    = (const float*)d_in[3];
    const float* W2    = (const float*)d_in[4];
    // d_in[5] = b2, unused by the force (only shifts the potential value)
    const int*   ids   = (const int*)d_in[6];

    float* q = (float*)d_out;                       // [BS, D]
    float* p = q + (size_t)BS_SZ * D_SZ;            // [BS, D]

    char* ws = (char*)d_ws;
    size_t o = 0;
    ushort_t* qb  = (ushort_t*)(ws + o); o += (size_t)BS_SZ * D_SZ * 2;   // 32 MB
    ushort_t* W1b = (ushort_t*)(ws + o); o += (size_t)H_SZ * D_SZ * 2;    // 2 MB
    ushort_t* W1T = (ushort_t*)(ws + o); o += (size_t)D_SZ * H_SZ * 2;    // 2 MB
    float* inv_mass = (float*)(ws + o);  o += S_SZ * 4;
    float* mass     = (float*)(ws + o);  o += S_SZ * 4;

    prep_w1<<<(H_SZ * D_SZ) / 256, 256, 0, stream>>>(W1, W1b, W1T);
    prep_mass<<<(S_SZ + 255) / 256, 256, 0, stream>>>(logm, inv_mass, mass);
    embed_kernel<<<BS_SZ, 128, 0, stream>>>(table, ids, mass, q, p, qb);

    leapfrog<<<256, 512, 0, stream>>>(W1b, W1T, b1, W2, ids, inv_mass, q, p, qb);
}

// Round 9
// 1540.299 us; speedup vs baseline: 1.0718x; 1.0718x over previous
//
#include <hip/hip_runtime.h>

// ---------------- problem constants ----------------
#define D_SZ 512
#define S_SZ 1024
#define H_SZ 2048
#define BS_SZ 32768
#define H_STEP 0.1f
#define ROWS 128          // i-rows per block
#define HB 256            // h-block size
#define NHB 8             // H_SZ / HB

typedef __attribute__((ext_vector_type(4))) float f32x4;
typedef __attribute__((ext_vector_type(8))) short s16x8;
typedef __attribute__((ext_vector_type(4))) unsigned short u16x4;
typedef unsigned short ushort_t;

__device__ __forceinline__ ushort_t f2b(float f) {
    unsigned u = __float_as_uint(f);
    unsigned r = (u + 0x7FFFu + ((u >> 16) & 1u)) >> 16;
    return (ushort_t)r;
}

__device__ __forceinline__ void gload_lds16(const void* g, void* l) {
    __builtin_amdgcn_global_load_lds(
        (const __attribute__((address_space(1))) unsigned int*)g,
        (__attribute__((address_space(3))) unsigned int*)l, 16, 0, 0);
}

// ---------------- prep kernels ----------------
__global__ void prep_w1(const float* __restrict__ W1,
                        ushort_t* __restrict__ W1b,
                        ushort_t* __restrict__ W1T) {
    int idx = blockIdx.x * 256 + threadIdx.x;   // over H*D = 1M
    float v = W1[idx];
    ushort_t b = f2b(v);
    int h = idx >> 9;          // / 512
    int d = idx & 511;
    W1b[idx] = b;
    W1T[(size_t)d * H_SZ + h] = b;
}

__global__ void prep_mass(const float* __restrict__ logm,
                          float* __restrict__ inv_mass,
                          float* __restrict__ mass) {
    int s = blockIdx.x * 256 + threadIdx.x;
    if (s < S_SZ) {
        float lm = logm[s];
        mass[s] = expf(lm);
        inv_mass[s] = expf(-lm);
    }
}

// ---------------- embedding + p0 ----------------
__global__ void embed_kernel(const float* __restrict__ table,
                             const int* __restrict__ ids,
                             const float* __restrict__ mass,
                             float* __restrict__ q,
                             float* __restrict__ p,
                             ushort_t* __restrict__ qb) {
    int i = blockIdx.x;          // row index in [0, BS)
    int t = threadIdx.x;
    int s = i & (S_SZ - 1);
    int id = ids[i];
    int idp = (s == 0) ? id : ids[i - 1];   // s==0: prev = self -> vel 0
    float mk = (id != 0) ? 1.f : 0.f;
    float ms = mass[s];
    int d0 = t * 4;

    f32x4 cur = {0.f, 0.f, 0.f, 0.f};
    f32x4 prv = {0.f, 0.f, 0.f, 0.f};
    if (id != 0)  cur = *(const f32x4*)(table + (size_t)id  * D_SZ + d0);
    if (idp != 0) prv = *(const f32x4*)(table + (size_t)idp * D_SZ + d0);

    size_t off = (size_t)i * D_SZ + d0;
    *(f32x4*)(q + off) = cur;
    u16x4 cb;
    cb[0] = f2b(cur[0]); cb[1] = f2b(cur[1]); cb[2] = f2b(cur[2]); cb[3] = f2b(cur[3]);
    *(u16x4*)(qb + off) = cb;

    f32x4 pv;
    pv[0] = ms * (cur[0] - prv[0]) * mk;
    pv[1] = ms * (cur[1] - prv[1]) * mk;
    pv[2] = ms * (cur[2] - prv[2]) * mk;
    pv[3] = ms * (cur[3] - prv[3]) * mk;
    *(f32x4*)(p + off) = pv;
}

// =====================================================================
// Fused row-local leapfrog v2: grid 256 x 512 thr, block owns 128 rows.
// Per force, per h-block (HB=256):
//   GEMM1: C1[256h][128i] = W1b_hb x qb  (K=512, 16 kt, wave 64x64, 16 MFMA/phase)
//   sech2 epilogue -> Ub in staged-tile format [8 kt][128 i][32 h], slot-XOR
//   GEMM2: G[512d][128i] += W1T x Ub     (K=256/hb, 8 kt x 2 d-halves,
//                                          wave 64x64 per half, 16 MFMA/phase)
// acc2[8][4] (=128 VGPR) persists across hb; leapfrog epilogue RMWs p/q.
// Counted vmcnt: STG1=3 loads -> vmcnt(3); STG2=2 loads -> vmcnt(2).
// All global stores only cross vmcnt(0) boundaries.  LDS = 144 KB.
// =====================================================================
__global__ __launch_bounds__(512, 2) void leapfrog(
        const ushort_t* __restrict__ W1b,   // [2048, 512]
        const ushort_t* __restrict__ W1T,   // [512, 2048]
        const float* __restrict__ b1,
        const float* __restrict__ W2,
        const int* __restrict__ ids,
        const float* __restrict__ inv_mass,
        float* __restrict__ q,
        float* __restrict__ p,
        ushort_t* __restrict__ qb) {
    __shared__ __align__(16) ushort_t g1A[2][256 * 32];   // 32 KB  W1b tiles
    __shared__ __align__(16) ushort_t g1B[2][128 * 32];   // 16 KB  qb tiles
    __shared__ __align__(16) ushort_t g2A[2][256 * 32];   // 32 KB  W1T tiles (d-half)
    __shared__ __align__(16) ushort_t Ub[8 * 128 * 32];   // 64 KB  U, tile format

    const int tid = threadIdx.x;
    const int lane = tid & 63, wid = tid >> 6;
    const int wg = wid >> 1, wi = wid & 1;     // 4 (h/d) x 2 (i) wave grid
    const int lr = lane & 15, lk = lane >> 4;

    const long i0 = (long)blockIdx.x * ROWS;

    // staging thread mapping (T2 swizzle, proven since R3):
    // chunk row r0 = tid>>2, 16B-slot kc = tid&3, source slot kcs = kc^((r0>>1)&3)
    const int r0  = tid >> 2;
    const int kc  = tid & 3;
    const int kcs = kc ^ ((r0 >> 1) & 3);
    const ushort_t* gqb  = qb  + (i0 + r0) * (long)D_SZ + kcs * 8;
    const ushort_t* gW1b = W1b + (long)r0 * D_SZ + kcs * 8;
    const ushort_t* gW1T = W1T + (long)r0 * H_SZ + kcs * 8;

    // ds_read swizzled k-slot
    const int lswz = (lk ^ ((lr >> 1) & 3)) * 8;
    const int swzkey = (lr >> 1) & 3;

    // STG1: 3 loads (W1b rows hb*256+r0, +128; qb row r0), tile kt
#define STG1(hb, kt) { int _b = (kt) & 1; \
    gload_lds16(gW1b + ((long)(hb) * 256      ) * D_SZ + (kt) * 32, &g1A[_b][tid * 8]); \
    gload_lds16(gW1b + ((long)(hb) * 256 + 128) * D_SZ + (kt) * 32, &g1A[_b][(tid + 512) * 8]); \
    gload_lds16(gqb + (kt) * 32,                                    &g1B[_b][tid * 8]); }
    // STG2: 2 loads (W1T rows dh*256+r0, +128), k = hb*256 + kt*32
#define STG2(hb, dh, kt, buf) { \
    gload_lds16(gW1T + ((long)(dh) * 256      ) * H_SZ + (hb) * 256 + (kt) * 32, &g2A[buf][tid * 8]); \
    gload_lds16(gW1T + ((long)(dh) * 256 + 128) * H_SZ + (hb) * 256 + (kt) * 32, &g2A[buf][(tid + 512) * 8]); }

    #pragma unroll 1
    for (int j = 0; j < 6; ++j) {
        const float coef = (j == 0 || j == 5) ? 0.05f : 0.1f;
        const int do_q = (j < 5);

        f32x4 acc2[8][4];
        #pragma unroll
        for (int m = 0; m < 8; ++m)
            #pragma unroll
            for (int n = 0; n < 4; ++n)
                acc2[m][n] = (f32x4){0.f, 0.f, 0.f, 0.f};

        #pragma unroll 1
        for (int hb = 0; hb < NHB; ++hb) {
            // ================= GEMM1: C1[256h][128i], K=512 =================
            f32x4 acc1[4][4];
            #pragma unroll
            for (int m = 0; m < 4; ++m)
                #pragma unroll
                for (int n = 0; n < 4; ++n)
                    acc1[m][n] = (f32x4){0.f, 0.f, 0.f, 0.f};

            STG1(hb, 0);
            #pragma unroll 1
            for (int kt = 0; kt < 16; ++kt) {
                if (kt < 15) {
                    STG1(hb, kt + 1);
                    asm volatile("s_waitcnt vmcnt(3)" ::: "memory");
                } else {
                    asm volatile("s_waitcnt vmcnt(0)" ::: "memory");
                }
                __builtin_amdgcn_s_barrier();

                s16x8 a1[4], bf[4];
                #pragma unroll
                for (int m = 0; m < 4; ++m)
                    a1[m] = *(const s16x8*)&g1A[kt & 1][(wg * 64 + m * 16 + lr) * 32 + lswz];
                #pragma unroll
                for (int ni = 0; ni < 4; ++ni)
                    bf[ni] = *(const s16x8*)&g1B[kt & 1][(wi * 64 + ni * 16 + lr) * 32 + lswz];
                asm volatile("s_waitcnt lgkmcnt(0)" ::: "memory");
                __builtin_amdgcn_sched_barrier(0);
                __builtin_amdgcn_s_setprio(1);
                #pragma unroll
                for (int m = 0; m < 4; ++m)
                    #pragma unroll
                    for (int ni = 0; ni < 4; ++ni)
                        acc1[m][ni] = __builtin_amdgcn_mfma_f32_16x16x32_bf16(a1[m], bf[ni], acc1[m][ni], 0, 0, 0);
                __builtin_amdgcn_s_setprio(0);
                __builtin_amdgcn_s_barrier();
            }

            // ---- U epilogue -> Ub tile format [kt32][i][32], slot-XOR by i ----
            #pragma unroll
            for (int mh = 0; mh < 4; ++mh) {
                int h0 = wg * 64 + mh * 16 + lk * 4;          // local h in [0,256)
                f32x4 b1v = *(const f32x4*)(b1 + hb * HB + h0);
                f32x4 w2v = *(const f32x4*)(W2 + hb * HB + h0);
                int kt32 = h0 >> 5;
                int slot = (h0 >> 3) & 3;
                int e    = h0 & 7;
                int pb   = kt32 * 4096 + (slot ^ swzkey) * 8 + e;
                #pragma unroll
                for (int ni = 0; ni < 4; ++ni) {
                    int i = wi * 64 + ni * 16 + lr;
                    u16x4 ub;
                    #pragma unroll
                    for (int jj = 0; jj < 4; ++jj) {
                        float uu = acc1[mh][ni][jj] + b1v[jj];
                        float e2 = __expf(-2.0f * fabsf(uu));
                        float rc = 1.0f / (1.0f + e2);
                        ub[jj] = f2b(4.0f * e2 * rc * rc * w2v[jj]);
                    }
                    *(u16x4*)&Ub[i * 32 + pb] = ub;
                }
            }
            // prestage GEMM2 (hides L2 latency under the epilogue VALU + barrier)
            STG2(hb, 0, 0, 0);
            asm volatile("s_waitcnt lgkmcnt(0)" ::: "memory");
            __builtin_amdgcn_s_barrier();

            // ========== GEMM2: G[512d][128i] += W1T x Ub, K=256, 2 d-halves ==========
            #pragma unroll 1
            for (int kt = 0; kt < 8; ++kt) {
                s16x8 b2[4];
                #pragma unroll
                for (int ni = 0; ni < 4; ++ni)
                    b2[ni] = *(const s16x8*)&Ub[kt * 4096 + (wi * 64 + ni * 16 + lr) * 32 + lswz];
                #pragma unroll
                for (int dh = 0; dh < 2; ++dh) {
                    int s = kt * 2 + dh;
                    if (s < 15) {
                        int sn = s + 1;
                        STG2(hb, sn & 1, sn >> 1, sn & 1);
                        asm volatile("s_waitcnt vmcnt(2)" ::: "memory");
                    } else {
                        asm volatile("s_waitcnt vmcnt(0)" ::: "memory");
                    }
                    __builtin_amdgcn_s_barrier();

                    s16x8 a2[4];
                    #pragma unroll
                    for (int md = 0; md < 4; ++md)
                        a2[md] = *(const s16x8*)&g2A[s & 1][(wg * 64 + md * 16 + lr) * 32 + lswz];
                    asm volatile("s_waitcnt lgkmcnt(0)" ::: "memory");
                    __builtin_amdgcn_sched_barrier(0);
                    __builtin_amdgcn_s_setprio(1);
                    #pragma unroll
                    for (int md = 0; md < 4; ++md)
                        #pragma unroll
                        for (int ni = 0; ni < 4; ++ni)
                            acc2[dh * 4 + md][ni] = __builtin_amdgcn_mfma_f32_16x16x32_bf16(a2[md], b2[ni], acc2[dh * 4 + md][ni], 0, 0, 0);
                    __builtin_amdgcn_s_setprio(0);
                    __builtin_amdgcn_s_barrier();
                }
            }
        }

        // ================= leapfrog update =================
        #pragma unroll
        for (int ni = 0; ni < 4; ++ni) {
            long gi = i0 + wi * 64 + ni * 16 + lr;
            int id = ids[gi];
            float cm = (id != 0) ? coef : 0.f;
            float hm = (id != 0) ? H_STEP : 0.f;
            float im = inv_mass[(int)(gi & (S_SZ - 1))];
            #pragma unroll
            for (int dh = 0; dh < 2; ++dh) {
                #pragma unroll
                for (int md = 0; md < 4; ++md) {
                    int d0 = dh * 256 + wg * 64 + md * 16 + lk * 4;
                    size_t off = (size_t)gi * D_SZ + d0;
                    f32x4 pv = *(const f32x4*)(p + off);
                    #pragma unroll
                    for (int jj = 0; jj < 4; ++jj)
                        pv[jj] -= cm * acc2[dh * 4 + md][ni][jj];
                    *(f32x4*)(p + off) = pv;
                    if (do_q) {
                        f32x4 qv = *(const f32x4*)(q + off);
                        u16x4 qbv;
                        #pragma unroll
                        for (int jj = 0; jj < 4; ++jj) {
                            qv[jj] += hm * pv[jj] * im;
                            qbv[jj] = f2b(qv[jj]);
                        }
                        *(f32x4*)(q + off) = qv;
                        *(u16x4*)(qb + off) = qbv;
                    }
                }
            }
        }
        // drain stores: qb must be L2-visible before next force's gload_lds,
        // and counted vmcnt in next GEMM1 must not see store entries.
        asm volatile("s_waitcnt vmcnt(0)" ::: "memory");
        __builtin_amdgcn_s_barrier();
    }
#undef STG1
#undef STG2
}

// ---------------- host launch ----------------
extern "C" void kernel_launch(void* const* d_in, const int* in_sizes, int n_in,
                              void* d_out, int out_size, void* d_ws, size_t ws_size,
                              hipStream_t stream) {
    const float* table = (const float*)d_in[0];
    const float* logm  = (const float*)d_in[1];
    const float* W1    = (const float*)d_in[2];
    const float* b1    = (const float*)d_in[3];
    const float* W2    = (const float*)d_in[4];
    // d_in[5] = b2, unused by the force (only shifts the potential value)
    const int*   ids   = (const int*)d_in[6];

    float* q = (float*)d_out;                       // [BS, D]
    float* p = q + (size_t)BS_SZ * D_SZ;            // [BS, D]

    char* ws = (char*)d_ws;
    size_t o = 0;
    ushort_t* qb  = (ushort_t*)(ws + o); o += (size_t)BS_SZ * D_SZ * 2;   // 32 MB
    ushort_t* W1b = (ushort_t*)(ws + o); o += (size_t)H_SZ * D_SZ * 2;    // 2 MB
    ushort_t* W1T = (ushort_t*)(ws + o); o += (size_t)D_SZ * H_SZ * 2;    // 2 MB
    float* inv_mass = (float*)(ws + o);  o += S_SZ * 4;
    float* mass     = (float*)(ws + o);  o += S_SZ * 4;

    prep_w1<<<(H_SZ * D_SZ) / 256, 256, 0, stream>>>(W1, W1b, W1T);
    prep_mass<<<(S_SZ + 255) / 256, 256, 0, stream>>>(logm, inv_mass, mass);
    embed_kernel<<<BS_SZ, 128, 0, stream>>>(table, ids, mass, q, p, qb);

    leapfrog<<<256, 512, 0, stream>>>(W1b, W1T, b1, W2, ids, inv_mass, q, p, qb);
}

// Round 10
// 1326.615 us; speedup vs baseline: 1.2444x; 1.1611x over previous
//
#include <hip/hip_runtime.h>

// ---------------- problem constants ----------------
#define D_SZ 512
#define S_SZ 1024
#define H_SZ 2048
#define BS_SZ 32768
#define H_STEP 0.1f

typedef __attribute__((ext_vector_type(4))) float f32x4;
typedef __attribute__((ext_vector_type(8))) short s16x8;
typedef __attribute__((ext_vector_type(4))) unsigned short u16x4;
typedef unsigned short ushort_t;
typedef unsigned char u8;
typedef long long i64;

__device__ __forceinline__ ushort_t f2b(float f) {
    unsigned u = __float_as_uint(f);
    unsigned r = (u + 0x7FFFu + ((u >> 16) & 1u)) >> 16;
    return (ushort_t)r;
}

__device__ __forceinline__ void gload_lds16(const void* g, void* l) {
    __builtin_amdgcn_global_load_lds(
        (const __attribute__((address_space(1))) unsigned int*)g,
        (__attribute__((address_space(3))) unsigned int*)l, 16, 0, 0);
}

// ---------------- prep kernels ----------------
__global__ void prep_w1(const float* __restrict__ W1,
                        ushort_t* __restrict__ W1b) {
    int idx = blockIdx.x * 256 + threadIdx.x;   // over H*D = 1M
    W1b[idx] = f2b(W1[idx]);
}

// transpose W1 [2048h][512d] -> W1f8 [512d][2048h], fp8 e4m3, x8 scale
__global__ void prep_w1t8(const float* __restrict__ W1, u8* __restrict__ W1f8) {
    __shared__ float t[64][65];
    int hb = blockIdx.x >> 3;      // 0..31
    int db = blockIdx.x & 7;       // 0..7
    int tr = threadIdx.x >> 2;     // 0..63
    int tc = threadIdx.x & 3;      // 0..3
    const float* src = W1 + (size_t)(hb * 64 + tr) * D_SZ + db * 64 + tc * 16;
    #pragma unroll
    for (int j = 0; j < 16; j += 4) {
        f32x4 v = *(const f32x4*)(src + j);
        t[tr][tc * 16 + j + 0] = v[0];
        t[tr][tc * 16 + j + 1] = v[1];
        t[tr][tc * 16 + j + 2] = v[2];
        t[tr][tc * 16 + j + 3] = v[3];
    }
    __syncthreads();
    u8* dst = W1f8 + (size_t)(db * 64 + tr) * H_SZ + hb * 64 + tc * 16;
    #pragma unroll
    for (int j = 0; j < 16; j += 4) {
        int r = 0;
        r = __builtin_amdgcn_cvt_pk_fp8_f32(t[tc * 16 + j + 0][tr] * 8.0f,
                                            t[tc * 16 + j + 1][tr] * 8.0f, r, false);
        r = __builtin_amdgcn_cvt_pk_fp8_f32(t[tc * 16 + j + 2][tr] * 8.0f,
                                            t[tc * 16 + j + 3][tr] * 8.0f, r, true);
        *(int*)(dst + j) = r;
    }
}

__global__ void prep_mass(const float* __restrict__ logm,
                          float* __restrict__ inv_mass,
                          float* __restrict__ mass) {
    int s = blockIdx.x * 256 + threadIdx.x;
    if (s < S_SZ) {
        float lm = logm[s];
        mass[s] = expf(lm);
        inv_mass[s] = expf(-lm);
    }
}

// ---------------- embedding + p0 ----------------
__global__ void embed_kernel(const float* __restrict__ table,
                             const int* __restrict__ ids,
                             const float* __restrict__ mass,
                             float* __restrict__ q,
                             float* __restrict__ p,
                             ushort_t* __restrict__ qb) {
    int i = blockIdx.x;          // row index in [0, BS)
    int t = threadIdx.x;
    int s = i & (S_SZ - 1);
    int id = ids[i];
    int idp = (s == 0) ? id : ids[i - 1];   // s==0: prev = self -> vel 0
    float mk = (id != 0) ? 1.f : 0.f;
    float ms = mass[s];
    int d0 = t * 4;

    f32x4 cur = {0.f, 0.f, 0.f, 0.f};
    f32x4 prv = {0.f, 0.f, 0.f, 0.f};
    if (id != 0)  cur = *(const f32x4*)(table + (size_t)id  * D_SZ + d0);
    if (idp != 0) prv = *(const f32x4*)(table + (size_t)idp * D_SZ + d0);

    size_t off = (size_t)i * D_SZ + d0;
    *(f32x4*)(q + off) = cur;
    u16x4 cb;
    cb[0] = f2b(cur[0]); cb[1] = f2b(cur[1]); cb[2] = f2b(cur[2]); cb[3] = f2b(cur[3]);
    *(u16x4*)(qb + off) = cb;

    f32x4 pv;
    pv[0] = ms * (cur[0] - prv[0]) * mk;
    pv[1] = ms * (cur[1] - prv[1]) * mk;
    pv[2] = ms * (cur[2] - prv[2]) * mk;
    pv[3] = ms * (cur[3] - prv[3]) * mk;
    *(f32x4*)(p + off) = pv;
}

// =====================================================================
// force1 (bf16, R3-proven core): 256x256 tile, BK=32, 3 LDS bufs,
// counted vmcnt(4), T2 XOR-swizzle, setprio, XCD swizzle. 8 waves (2x4).
// C[r=h][c=i] = sum_k W1b[h,k]*qb[i,k].
// Epilogue: U[i,h] = fp8_e4m3(16 * sech2(C + b1[h]) * w2[h]).
// =====================================================================
__global__ __launch_bounds__(512, 2) void gemm_f1(
        const ushort_t* __restrict__ A,     // W1b [2048, 512]
        const ushort_t* __restrict__ B,     // qb  [BS, 512]
        const float* __restrict__ b1,
        const float* __restrict__ W2,
        u8* __restrict__ U) {
    constexpr int KLEN = 512;
    constexpr int NT = KLEN / 32;
    __shared__ __align__(16) ushort_t lA[3][256 * 32];
    __shared__ __align__(16) ushort_t lB[3][256 * 32];

    const int tid = threadIdx.x;
    const int lane = tid & 63, wid = tid >> 6;
    const int wm = wid >> 2, wn = wid & 3;
    const int lr = lane & 15, lk = lane >> 4;

    int wgid = ((int)blockIdx.x & 7) * 128 + ((int)blockIdx.x >> 3);  // nwg=1024
    int bxA = wgid & 7;          // 8 h-blocks
    int by  = wgid >> 3;         // 128 i-blocks
    const long a0 = (long)bxA * 256;
    const long b0 = (long)by * 256;

    const int r1  = tid >> 2;
    const int kc  = tid & 3;
    const int kcs = kc ^ ((r1 >> 1) & 3);
    const ushort_t* gA1 = A + (a0 + r1) * (long)KLEN + kcs * 8;
    const ushort_t* gA2 = gA1 + (long)128 * KLEN;
    const ushort_t* gB1 = B + (b0 + r1) * (long)KLEN + kcs * 8;
    const ushort_t* gB2 = gB1 + (long)128 * KLEN;
    const int ld1 = tid * 8;
    const int ld2 = (tid + 512) * 8;

#define STAGE_A(t) { int _b = (t) % 3;                         \
    gload_lds16(gA1 + (long)(t) * 32, &lA[_b][ld1]);           \
    gload_lds16(gA2 + (long)(t) * 32, &lA[_b][ld2]); }
#define STAGE_B(t) { int _b = (t) % 3;                         \
    gload_lds16(gB1 + (long)(t) * 32, &lB[_b][ld1]);           \
    gload_lds16(gB2 + (long)(t) * 32, &lB[_b][ld2]); }

    f32x4 acc[8][4];
    #pragma unroll
    for (int m = 0; m < 8; ++m)
        #pragma unroll
        for (int n = 0; n < 4; ++n)
            acc[m][n] = (f32x4){0.f, 0.f, 0.f, 0.f};

    const int lks8 = (lk ^ ((lr >> 1) & 3)) * 8;
    const int roA = (wm * 128 + lr) * 32 + lks8;
    const int roB = (wn * 64 + lr) * 32 + lks8;

    STAGE_A(0); STAGE_B(0);
    STAGE_A(1); STAGE_B(1);

    for (int t = 0; t < NT; ++t) {
        const int buf = t % 3;
        const ushort_t* bA = &lA[buf][0];
        const ushort_t* bB = &lB[buf][0];
        asm volatile("s_waitcnt vmcnt(4)" ::: "memory");
        __builtin_amdgcn_s_barrier();

        s16x8 av[4], bv[4];
        #pragma unroll
        for (int m = 0; m < 4; ++m) av[m] = *(const s16x8*)&bA[roA + m * 512];
        #pragma unroll
        for (int n = 0; n < 4; ++n) bv[n] = *(const s16x8*)&bB[roB + n * 512];
        if (t + 2 < NT) STAGE_A(t + 2);
        __builtin_amdgcn_s_setprio(1);
        #pragma unroll
        for (int m = 0; m < 4; ++m)
            #pragma unroll
            for (int n = 0; n < 4; ++n)
                acc[m][n] = __builtin_amdgcn_mfma_f32_16x16x32_bf16(av[m], bv[n], acc[m][n], 0, 0, 0);
        __builtin_amdgcn_s_setprio(0);
        __builtin_amdgcn_s_barrier();

        s16x8 av2[4];
        #pragma unroll
        for (int m = 0; m < 4; ++m) av2[m] = *(const s16x8*)&bA[roA + (m + 4) * 512];
        if (t + 2 < NT) STAGE_B(t + 2);
        __builtin_amdgcn_s_setprio(1);
        #pragma unroll
        for (int m = 0; m < 4; ++m)
            #pragma unroll
            for (int n = 0; n < 4; ++n)
                acc[m + 4][n] = __builtin_amdgcn_mfma_f32_16x16x32_bf16(av2[m], bv[n], acc[m + 4][n], 0, 0, 0);
        __builtin_amdgcn_s_setprio(0);
    }
#undef STAGE_A
#undef STAGE_B

    // epilogue: U[i,h] = fp8(16*sech2(C+b1)*w2)  (4 consecutive h per store)
    #pragma unroll
    for (int m = 0; m < 8; ++m) {
        long h0 = a0 + wm * 128 + m * 16 + lk * 4;
        f32x4 b1v = *(const f32x4*)(b1 + h0);
        f32x4 w2v = *(const f32x4*)(W2 + h0);
        #pragma unroll
        for (int n = 0; n < 4; ++n) {
            long i = b0 + wn * 64 + n * 16 + lr;
            float v[4];
            #pragma unroll
            for (int j = 0; j < 4; ++j) {
                float uu = acc[m][n][j] + b1v[j];
                // 16*sech^2(u)*w2 = 64*e/(1+e)^2*w2, e = exp(-2|u|)
                float e = __expf(-2.0f * fabsf(uu));
                float rc = 1.0f / (1.0f + e);
                v[j] = 64.0f * e * rc * rc * w2v[j];
            }
            int pk = 0;
            pk = __builtin_amdgcn_cvt_pk_fp8_f32(v[0], v[1], pk, false);
            pk = __builtin_amdgcn_cvt_pk_fp8_f32(v[2], v[3], pk, true);
            *(int*)(U + i * H_SZ + h0) = pk;
        }
    }
}

// =====================================================================
// force2 (fp8 x fp8): grid 256, block owns i-tile 128 x full d=512.
// A = W1f8 [512,2048] (L2-resident, x8), B = Uf8 i-tile (x16), K=2048.
// BK=64 (64B/row, 4x16B slots, same XOR swizzle), 2 LDS bufs (80 KB),
// counted vmcnt(5). 8 waves = 4(d) x 2(i), wave tile 128d x 64i,
// 64 mfma_fp8_fp8 per K-tile per wave. Epilogue: leapfrog p/q update
// with coef/128 descaling.
// =====================================================================
__global__ __launch_bounds__(512, 2) void gemm_f2(
        const u8* __restrict__ W1f8,   // [512][2048]
        const u8* __restrict__ Uf8,    // [BS][2048]
        const int* __restrict__ ids,
        const float* __restrict__ inv_mass,
        float* __restrict__ q,
        float* __restrict__ p,
        ushort_t* __restrict__ qb,
        float coef, int do_q) {
    __shared__ __align__(16) u8 lA[2][512 * 64];   // 64 KB
    __shared__ __align__(16) u8 lB[2][128 * 64];   // 16 KB

    const int tid = threadIdx.x;
    const int lane = tid & 63, wid = tid >> 6;
    const int dg = wid >> 1, ig = wid & 1;     // 4 (d) x 2 (i)
    const int lr = lane & 15, lk = lane >> 4;

    int wgid = ((int)blockIdx.x & 7) * 32 + ((int)blockIdx.x >> 3);
    const long b0 = (long)wgid * 128;

    const int r0  = tid >> 2;
    const int kc  = tid & 3;
    const int kcs = kc ^ ((r0 >> 1) & 3);
    const u8* gA = W1f8 + (long)r0 * H_SZ + kcs * 16;
    const u8* gB = Uf8 + (b0 + r0) * (long)H_SZ + kcs * 16;

#define STG(t) { int _b = (t) & 1; \
    gload_lds16(gA + (long)(t) * 64,                 &lA[_b][tid * 16]); \
    gload_lds16(gA + 128L * H_SZ + (long)(t) * 64,   &lA[_b][(tid + 512) * 16]); \
    gload_lds16(gA + 256L * H_SZ + (long)(t) * 64,   &lA[_b][(tid + 1024) * 16]); \
    gload_lds16(gA + 384L * H_SZ + (long)(t) * 64,   &lA[_b][(tid + 1536) * 16]); \
    gload_lds16(gB + (long)(t) * 64,                 &lB[_b][tid * 16]); }

    f32x4 acc[8][4];
    #pragma unroll
    for (int m = 0; m < 8; ++m)
        #pragma unroll
        for (int n = 0; n < 4; ++n)
            acc[m][n] = (f32x4){0.f, 0.f, 0.f, 0.f};

    const int key = (lr >> 1) & 3;

    STG(0);
    const int NT = H_SZ / 64;   // 32
    for (int t = 0; t < NT; ++t) {
        if (t + 1 < NT) {
            STG(t + 1);
            asm volatile("s_waitcnt vmcnt(5)" ::: "memory");
        } else {
            asm volatile("s_waitcnt vmcnt(0)" ::: "memory");
        }
        __builtin_amdgcn_s_barrier();

        const u8* bA = &lA[t & 1][0];
        const u8* bB = &lB[t & 1][0];
        #pragma unroll
        for (int x = 0; x < 2; ++x) {
            // 8-byte fragment at k32-subtile x: byte slot c = x*2 + (lk>>1),
            // swizzled addr = row*64 + ((c^key)*16) + (lk&1)*8
            const int so = (((x * 2 + (lk >> 1)) ^ key) * 16) + (lk & 1) * 8;
            i64 a[8], b[4];
            #pragma unroll
            for (int m = 0; m < 8; ++m)
                a[m] = *(const i64*)&bA[(dg * 128 + m * 16 + lr) * 64 + so];
            #pragma unroll
            for (int n = 0; n < 4; ++n)
                b[n] = *(const i64*)&bB[(ig * 64 + n * 16 + lr) * 64 + so];
            asm volatile("s_waitcnt lgkmcnt(0)" ::: "memory");
            __builtin_amdgcn_sched_barrier(0);
            __builtin_amdgcn_s_setprio(1);
            #pragma unroll
            for (int m = 0; m < 8; ++m)
                #pragma unroll
                for (int n = 0; n < 4; ++n)
                    acc[m][n] = __builtin_amdgcn_mfma_f32_16x16x32_fp8_fp8(a[m], b[n], acc[m][n], 0, 0, 0);
            __builtin_amdgcn_s_setprio(0);
        }
        __builtin_amdgcn_s_barrier();
    }
#undef STG

    // epilogue: p -= (coef/128)*mask*G ; q += 0.1*p/m*mask ; qb = bf16(q)
    const float cs = coef * (1.0f / 128.0f);
    #pragma unroll
    for (int n = 0; n < 4; ++n) {
        long i = b0 + ig * 64 + n * 16 + lr;
        int id = ids[i];
        float cm = (id != 0) ? cs : 0.f;
        float hm = (id != 0) ? H_STEP : 0.f;
        float im = inv_mass[(int)(i & (S_SZ - 1))];
        #pragma unroll
        for (int m = 0; m < 8; ++m) {
            long d0 = dg * 128 + m * 16 + lk * 4;
            size_t off = (size_t)i * D_SZ + d0;
            f32x4 pv = *(const f32x4*)(p + off);
            #pragma unroll
            for (int j = 0; j < 4; ++j)
                pv[j] -= cm * acc[m][n][j];
            *(f32x4*)(p + off) = pv;
            if (do_q) {
                f32x4 qv = *(const f32x4*)(q + off);
                u16x4 qbv;
                #pragma unroll
                for (int j = 0; j < 4; ++j) {
                    qv[j] += hm * pv[j] * im;
                    qbv[j] = f2b(qv[j]);
                }
                *(f32x4*)(q + off) = qv;
                *(u16x4*)(qb + off) = qbv;
            }
        }
    }
}

// ---------------- host launch ----------------
extern "C" void kernel_launch(void* const* d_in, const int* in_sizes, int n_in,
                              void* d_out, int out_size, void* d_ws, size_t ws_size,
                              hipStream_t stream) {
    const float* table = (const float*)d_in[0];
    const float* logm  = (const float*)d_in[1];
    const float* W1    = (const float*)d_in[2];
    const float* b1    = (const float*)d_in[3];
    const float* W2    = (const float*)d_in[4];
    // d_in[5] = b2, unused by the force (only shifts the potential value)
    const int*   ids   = (const int*)d_in[6];

    float* q = (float*)d_out;                       // [BS, D]
    float* p = q + (size_t)BS_SZ * D_SZ;            // [BS, D]

    char* ws = (char*)d_ws;
    size_t o = 0;
    ushort_t* qb  = (ushort_t*)(ws + o); o += (size_t)BS_SZ * D_SZ * 2;   // 32 MB
    u8* Uf8       = (u8*)(ws + o);       o += (size_t)BS_SZ * H_SZ;       // 64 MB
    ushort_t* W1b = (ushort_t*)(ws + o); o += (size_t)H_SZ * D_SZ * 2;    // 2 MB
    u8* W1f8      = (u8*)(ws + o);       o += (size_t)D_SZ * H_SZ;        // 1 MB
    float* inv_mass = (float*)(ws + o);  o += S_SZ * 4;
    float* mass     = (float*)(ws + o);  o += S_SZ * 4;

    prep_w1<<<(H_SZ * D_SZ) / 256, 256, 0, stream>>>(W1, W1b);
    prep_w1t8<<<256, 256, 0, stream>>>(W1, W1f8);
    prep_mass<<<(S_SZ + 255) / 256, 256, 0, stream>>>(logm, inv_mass, mass);
    embed_kernel<<<BS_SZ, 128, 0, stream>>>(table, ids, mass, q, p, qb);

    // 6 distinct force evals: j=0 -> +0.05*f(q0); j=1..4 -> +0.1*f(qj); j=5 -> +0.05*f(q5)
    for (int j = 0; j < 6; ++j) {
        gemm_f1<<<1024, 512, 0, stream>>>(W1b, qb, b1, W2, Uf8);
        float coef = (j == 0 || j == 5) ? 0.05f : 0.1f;
        gemm_f2<<<256, 512, 0, stream>>>(
            W1f8, Uf8, ids, inv_mass, q, p, qb, coef, (j < 5) ? 1 : 0);
    }
}

// Round 11
// 1263.977 us; speedup vs baseline: 1.3061x; 1.0496x over previous
//
#include <hip/hip_runtime.h>

// ---------------- problem constants ----------------
#define D_SZ 512
#define S_SZ 1024
#define H_SZ 2048
#define BS_SZ 32768
#define H_STEP 0.1f

typedef __attribute__((ext_vector_type(4))) float f32x4;
typedef __attribute__((ext_vector_type(8))) short s16x8;
typedef __attribute__((ext_vector_type(4))) unsigned short u16x4;
typedef unsigned short ushort_t;
typedef unsigned char u8;
typedef long long i64;

__device__ __forceinline__ ushort_t f2b(float f) {
    unsigned u = __float_as_uint(f);
    unsigned r = (u + 0x7FFFu + ((u >> 16) & 1u)) >> 16;
    return (ushort_t)r;
}

__device__ __forceinline__ void gload_lds16(const void* g, void* l) {
    __builtin_amdgcn_global_load_lds(
        (const __attribute__((address_space(1))) unsigned int*)g,
        (__attribute__((address_space(3))) unsigned int*)l, 16, 0, 0);
}

// ---------------- prep kernels ----------------
__global__ void prep_w1(const float* __restrict__ W1,
                        ushort_t* __restrict__ W1b) {
    int idx = blockIdx.x * 256 + threadIdx.x;   // over H*D = 1M
    W1b[idx] = f2b(W1[idx]);
}

// transpose W1 [2048h][512d] -> W1f8 [512d][2048h], fp8 e4m3, x8 scale
__global__ void prep_w1t8(const float* __restrict__ W1, u8* __restrict__ W1f8) {
    __shared__ float t[64][65];
    int hb = blockIdx.x >> 3;      // 0..31
    int db = blockIdx.x & 7;       // 0..7
    int tr = threadIdx.x >> 2;     // 0..63
    int tc = threadIdx.x & 3;      // 0..3
    const float* src = W1 + (size_t)(hb * 64 + tr) * D_SZ + db * 64 + tc * 16;
    #pragma unroll
    for (int j = 0; j < 16; j += 4) {
        f32x4 v = *(const f32x4*)(src + j);
        t[tr][tc * 16 + j + 0] = v[0];
        t[tr][tc * 16 + j + 1] = v[1];
        t[tr][tc * 16 + j + 2] = v[2];
        t[tr][tc * 16 + j + 3] = v[3];
    }
    __syncthreads();
    u8* dst = W1f8 + (size_t)(db * 64 + tr) * H_SZ + hb * 64 + tc * 16;
    #pragma unroll
    for (int j = 0; j < 16; j += 4) {
        int r = 0;
        r = __builtin_amdgcn_cvt_pk_fp8_f32(t[tc * 16 + j + 0][tr] * 8.0f,
                                            t[tc * 16 + j + 1][tr] * 8.0f, r, false);
        r = __builtin_amdgcn_cvt_pk_fp8_f32(t[tc * 16 + j + 2][tr] * 8.0f,
                                            t[tc * 16 + j + 3][tr] * 8.0f, r, true);
        *(int*)(dst + j) = r;
    }
}

__global__ void prep_mass(const float* __restrict__ logm,
                          float* __restrict__ inv_mass,
                          float* __restrict__ mass) {
    int s = blockIdx.x * 256 + threadIdx.x;
    if (s < S_SZ) {
        float lm = logm[s];
        mass[s] = expf(lm);
        inv_mass[s] = expf(-lm);
    }
}

// ---------------- embedding + p0 ----------------
__global__ void embed_kernel(const float* __restrict__ table,
                             const int* __restrict__ ids,
                             const float* __restrict__ mass,
                             float* __restrict__ q,
                             float* __restrict__ p,
                             ushort_t* __restrict__ qb) {
    int i = blockIdx.x;          // row index in [0, BS)
    int t = threadIdx.x;
    int s = i & (S_SZ - 1);
    int id = ids[i];
    int idp = (s == 0) ? id : ids[i - 1];   // s==0: prev = self -> vel 0
    float mk = (id != 0) ? 1.f : 0.f;
    float ms = mass[s];
    int d0 = t * 4;

    f32x4 cur = {0.f, 0.f, 0.f, 0.f};
    f32x4 prv = {0.f, 0.f, 0.f, 0.f};
    if (id != 0)  cur = *(const f32x4*)(table + (size_t)id  * D_SZ + d0);
    if (idp != 0) prv = *(const f32x4*)(table + (size_t)idp * D_SZ + d0);

    size_t off = (size_t)i * D_SZ + d0;
    *(f32x4*)(q + off) = cur;
    u16x4 cb;
    cb[0] = f2b(cur[0]); cb[1] = f2b(cur[1]); cb[2] = f2b(cur[2]); cb[3] = f2b(cur[3]);
    *(u16x4*)(qb + off) = cb;

    f32x4 pv;
    pv[0] = ms * (cur[0] - prv[0]) * mk;
    pv[1] = ms * (cur[1] - prv[1]) * mk;
    pv[2] = ms * (cur[2] - prv[2]) * mk;
    pv[3] = ms * (cur[3] - prv[3]) * mk;
    *(f32x4*)(p + off) = pv;
}

// =====================================================================
// force1 (bf16, R3-proven core): 256x256 tile, BK=32, 3 LDS bufs,
// counted vmcnt(4), T2 XOR-swizzle, setprio, XCD swizzle. 8 waves (2x4).
// C[r=h][c=i] = sum_k W1b[h,k]*qb[i,k].
// Epilogue: U[i,h] = fp8_e4m3(16 * sech2(C + b1[h]) * w2[h]).
// =====================================================================
__global__ __launch_bounds__(512, 2) void gemm_f1(
        const ushort_t* __restrict__ A,     // W1b [2048, 512]
        const ushort_t* __restrict__ B,     // qb  [BS, 512]
        const float* __restrict__ b1,
        const float* __restrict__ W2,
        u8* __restrict__ U) {
    constexpr int KLEN = 512;
    constexpr int NT = KLEN / 32;
    __shared__ __align__(16) ushort_t lA[3][256 * 32];
    __shared__ __align__(16) ushort_t lB[3][256 * 32];

    const int tid = threadIdx.x;
    const int lane = tid & 63, wid = tid >> 6;
    const int wm = wid >> 2, wn = wid & 3;
    const int lr = lane & 15, lk = lane >> 4;

    int wgid = ((int)blockIdx.x & 7) * 128 + ((int)blockIdx.x >> 3);  // nwg=1024
    int bxA = wgid & 7;          // 8 h-blocks
    int by  = wgid >> 3;         // 128 i-blocks
    const long a0 = (long)bxA * 256;
    const long b0 = (long)by * 256;

    const int r1  = tid >> 2;
    const int kc  = tid & 3;
    const int kcs = kc ^ ((r1 >> 1) & 3);
    const ushort_t* gA1 = A + (a0 + r1) * (long)KLEN + kcs * 8;
    const ushort_t* gA2 = gA1 + (long)128 * KLEN;
    const ushort_t* gB1 = B + (b0 + r1) * (long)KLEN + kcs * 8;
    const ushort_t* gB2 = gB1 + (long)128 * KLEN;
    const int ld1 = tid * 8;
    const int ld2 = (tid + 512) * 8;

#define STAGE_A(t) { int _b = (t) % 3;                         \
    gload_lds16(gA1 + (long)(t) * 32, &lA[_b][ld1]);           \
    gload_lds16(gA2 + (long)(t) * 32, &lA[_b][ld2]); }
#define STAGE_B(t) { int _b = (t) % 3;                         \
    gload_lds16(gB1 + (long)(t) * 32, &lB[_b][ld1]);           \
    gload_lds16(gB2 + (long)(t) * 32, &lB[_b][ld2]); }

    f32x4 acc[8][4];
    #pragma unroll
    for (int m = 0; m < 8; ++m)
        #pragma unroll
        for (int n = 0; n < 4; ++n)
            acc[m][n] = (f32x4){0.f, 0.f, 0.f, 0.f};

    const int lks8 = (lk ^ ((lr >> 1) & 3)) * 8;
    const int roA = (wm * 128 + lr) * 32 + lks8;
    const int roB = (wn * 64 + lr) * 32 + lks8;

    STAGE_A(0); STAGE_B(0);
    STAGE_A(1); STAGE_B(1);

    for (int t = 0; t < NT; ++t) {
        const int buf = t % 3;
        const ushort_t* bA = &lA[buf][0];
        const ushort_t* bB = &lB[buf][0];
        asm volatile("s_waitcnt vmcnt(4)" ::: "memory");
        __builtin_amdgcn_s_barrier();

        s16x8 av[4], bv[4];
        #pragma unroll
        for (int m = 0; m < 4; ++m) av[m] = *(const s16x8*)&bA[roA + m * 512];
        #pragma unroll
        for (int n = 0; n < 4; ++n) bv[n] = *(const s16x8*)&bB[roB + n * 512];
        if (t + 2 < NT) STAGE_A(t + 2);
        __builtin_amdgcn_s_setprio(1);
        #pragma unroll
        for (int m = 0; m < 4; ++m)
            #pragma unroll
            for (int n = 0; n < 4; ++n)
                acc[m][n] = __builtin_amdgcn_mfma_f32_16x16x32_bf16(av[m], bv[n], acc[m][n], 0, 0, 0);
        __builtin_amdgcn_s_setprio(0);
        __builtin_amdgcn_s_barrier();

        s16x8 av2[4];
        #pragma unroll
        for (int m = 0; m < 4; ++m) av2[m] = *(const s16x8*)&bA[roA + (m + 4) * 512];
        if (t + 2 < NT) STAGE_B(t + 2);
        __builtin_amdgcn_s_setprio(1);
        #pragma unroll
        for (int m = 0; m < 4; ++m)
            #pragma unroll
            for (int n = 0; n < 4; ++n)
                acc[m + 4][n] = __builtin_amdgcn_mfma_f32_16x16x32_bf16(av2[m], bv[n], acc[m + 4][n], 0, 0, 0);
        __builtin_amdgcn_s_setprio(0);
    }
#undef STAGE_A
#undef STAGE_B

    // epilogue: U[i,h] = fp8(16*sech2(C+b1)*w2)  (4 consecutive h per store)
    #pragma unroll
    for (int m = 0; m < 8; ++m) {
        long h0 = a0 + wm * 128 + m * 16 + lk * 4;
        f32x4 b1v = *(const f32x4*)(b1 + h0);
        f32x4 w2v = *(const f32x4*)(W2 + h0);
        #pragma unroll
        for (int n = 0; n < 4; ++n) {
            long i = b0 + wn * 64 + n * 16 + lr;
            float v[4];
            #pragma unroll
            for (int j = 0; j < 4; ++j) {
                float uu = acc[m][n][j] + b1v[j];
                // 16*sech^2(u)*w2 = 64*e/(1+e)^2*w2, e = exp(-2|u|)
                float e = __expf(-2.0f * fabsf(uu));
                float rc = 1.0f / (1.0f + e);
                v[j] = 64.0f * e * rc * rc * w2v[j];
            }
            int pk = 0;
            pk = __builtin_amdgcn_cvt_pk_fp8_f32(v[0], v[1], pk, false);
            pk = __builtin_amdgcn_cvt_pk_fp8_f32(v[2], v[3], pk, true);
            *(int*)(U + i * H_SZ + h0) = pk;
        }
    }
}

// =====================================================================
// force2 (fp8 x fp8), v2: grid 512 = 2 d-halves x 256 i-tiles.
// Block = 256d x 128i, K=2048, BK=64. A = W1f8 d-half (L2-resident, x8),
// B = Uf8 i-tile (x16). LDS 48 KB, VGPR ~100 -> 2 blocks/CU for
// cross-block latency overlap. 8 waves = 4(d) x 2(i), wave 64d x 64i,
// 32 MFMA/tile between barriers. Counted vmcnt(3).
// Epilogue: leapfrog p/q update with coef/128 descaling.
// =====================================================================
__global__ __launch_bounds__(512, 2) void gemm_f2(
        const u8* __restrict__ W1f8,   // [512][2048]
        const u8* __restrict__ Uf8,    // [BS][2048]
        const int* __restrict__ ids,
        const float* __restrict__ inv_mass,
        float* __restrict__ q,
        float* __restrict__ p,
        ushort_t* __restrict__ qb,
        float coef, int do_q) {
    __shared__ __align__(16) u8 lA[2][256 * 64];   // 32 KB
    __shared__ __align__(16) u8 lB[2][128 * 64];   // 16 KB

    const int tid = threadIdx.x;
    const int lane = tid & 63, wid = tid >> 6;
    const int wd = wid >> 1, wi = wid & 1;     // 4 (d) x 2 (i)
    const int lr = lane & 15, lk = lane >> 4;

    // bijective XCD swizzle, nwg=512; d-half fastest (shares U i-tile in L2)
    int wgid = ((int)blockIdx.x & 7) * 64 + ((int)blockIdx.x >> 3);
    const int  dh = wgid & 1;
    const long a0 = (long)dh * 256;             // d base
    const long b0 = (long)(wgid >> 1) * 128;    // i base

    const int r0  = tid >> 2;                   // 0..127
    const int kc  = tid & 3;
    const int kcs = kc ^ ((r0 >> 1) & 3);
    const u8* gA = W1f8 + (a0 + r0) * (long)H_SZ + kcs * 16;
    const u8* gB = Uf8 + (b0 + r0) * (long)H_SZ + kcs * 16;

#define STG(t) { int _b = (t) & 1; \
    gload_lds16(gA + (long)(t) * 64,               &lA[_b][tid * 16]); \
    gload_lds16(gA + 128L * H_SZ + (long)(t) * 64, &lA[_b][(tid + 512) * 16]); \
    gload_lds16(gB + (long)(t) * 64,               &lB[_b][tid * 16]); }

    f32x4 acc[4][4];
    #pragma unroll
    for (int m = 0; m < 4; ++m)
        #pragma unroll
        for (int n = 0; n < 4; ++n)
            acc[m][n] = (f32x4){0.f, 0.f, 0.f, 0.f};

    const int key = (lr >> 1) & 3;

    STG(0);
    const int NT = H_SZ / 64;   // 32
    for (int t = 0; t < NT; ++t) {
        if (t + 1 < NT) {
            STG(t + 1);
            asm volatile("s_waitcnt vmcnt(3)" ::: "memory");
        } else {
            asm volatile("s_waitcnt vmcnt(0)" ::: "memory");
        }
        __builtin_amdgcn_s_barrier();

        const u8* bA = &lA[t & 1][0];
        const u8* bB = &lB[t & 1][0];
        #pragma unroll
        for (int x = 0; x < 2; ++x) {
            // 8B fragment, k32-subtile x: slot c = x*2 + (lk>>1), XOR key
            const int so = (((x * 2 + (lk >> 1)) ^ key) * 16) + (lk & 1) * 8;
            i64 a[4], b[4];
            #pragma unroll
            for (int m = 0; m < 4; ++m)
                a[m] = *(const i64*)&bA[(wd * 64 + m * 16 + lr) * 64 + so];
            #pragma unroll
            for (int n = 0; n < 4; ++n)
                b[n] = *(const i64*)&bB[(wi * 64 + n * 16 + lr) * 64 + so];
            asm volatile("s_waitcnt lgkmcnt(0)" ::: "memory");
            __builtin_amdgcn_sched_barrier(0);
            __builtin_amdgcn_s_setprio(1);
            #pragma unroll
            for (int m = 0; m < 4; ++m)
                #pragma unroll
                for (int n = 0; n < 4; ++n)
                    acc[m][n] = __builtin_amdgcn_mfma_f32_16x16x32_fp8_fp8(a[m], b[n], acc[m][n], 0, 0, 0);
            __builtin_amdgcn_s_setprio(0);
        }
        __builtin_amdgcn_s_barrier();
    }
#undef STG

    // epilogue: p -= (coef/128)*mask*G ; q += 0.1*p/m*mask ; qb = bf16(q)
    const float cs = coef * (1.0f / 128.0f);
    #pragma unroll
    for (int n = 0; n < 4; ++n) {
        long i = b0 + wi * 64 + n * 16 + lr;
        int id = ids[i];
        float cm = (id != 0) ? cs : 0.f;
        float hm = (id != 0) ? H_STEP : 0.f;
        float im = inv_mass[(int)(i & (S_SZ - 1))];
        #pragma unroll
        for (int m = 0; m < 4; ++m) {
            long d0 = a0 + wd * 64 + m * 16 + lk * 4;
            size_t off = (size_t)i * D_SZ + d0;
            f32x4 pv = *(const f32x4*)(p + off);
            #pragma unroll
            for (int j = 0; j < 4; ++j)
                pv[j] -= cm * acc[m][n][j];
            *(f32x4*)(p + off) = pv;
            if (do_q) {
                f32x4 qv = *(const f32x4*)(q + off);
                u16x4 qbv;
                #pragma unroll
                for (int j = 0; j < 4; ++j) {
                    qv[j] += hm * pv[j] * im;
                    qbv[j] = f2b(qv[j]);
                }
                *(f32x4*)(q + off) = qv;
                *(u16x4*)(qb + off) = qbv;
            }
        }
    }
}

// ---------------- host launch ----------------
extern "C" void kernel_launch(void* const* d_in, const int* in_sizes, int n_in,
                              void* d_out, int out_size, void* d_ws, size_t ws_size,
                              hipStream_t stream) {
    const float* table = (const float*)d_in[0];
    const float* logm  = (const float*)d_in[1];
    const float* W1    = (const float*)d_in[2];
    const float* b1    = (const float*)d_in[3];
    const float* W2    = (const float*)d_in[4];
    // d_in[5] = b2, unused by the force (only shifts the potential value)
    const int*   ids   = (const int*)d_in[6];

    float* q = (float*)d_out;                       // [BS, D]
    float* p = q + (size_t)BS_SZ * D_SZ;            // [BS, D]

    char* ws = (char*)d_ws;
    size_t o = 0;
    ushort_t* qb  = (ushort_t*)(ws + o); o += (size_t)BS_SZ * D_SZ * 2;   // 32 MB
    u8* Uf8       = (u8*)(ws + o);       o += (size_t)BS_SZ * H_SZ;       // 64 MB
    ushort_t* W1b = (ushort_t*)(ws + o); o += (size_t)H_SZ * D_SZ * 2;    // 2 MB
    u8* W1f8      = (u8*)(ws + o);       o += (size_t)D_SZ * H_SZ;        // 1 MB
    float* inv_mass = (float*)(ws + o);  o += S_SZ * 4;
    float* mass     = (float*)(ws + o);  o += S_SZ * 4;

    prep_w1<<<(H_SZ * D_SZ) / 256, 256, 0, stream>>>(W1, W1b);
    prep_w1t8<<<256, 256, 0, stream>>>(W1, W1f8);
    prep_mass<<<(S_SZ + 255) / 256, 256, 0, stream>>>(logm, inv_mass, mass);
    embed_kernel<<<BS_SZ, 128, 0, stream>>>(table, ids, mass, q, p, qb);

    // 6 distinct force evals: j=0 -> +0.05*f(q0); j=1..4 -> +0.1*f(qj); j=5 -> +0.05*f(q5)
    for (int j = 0; j < 6; ++j) {
        gemm_f1<<<1024, 512, 0, stream>>>(W1b, qb, b1, W2, Uf8);
        float coef = (j == 0 || j == 5) ? 0.05f : 0.1f;
        gemm_f2<<<512, 512, 0, stream>>>(
            W1f8, Uf8, ids, inv_mass, q, p, qb, coef, (j < 5) ? 1 : 0);
    }
}

// Round 12
// 1127.187 us; speedup vs baseline: 1.4645x; 1.1214x over previous
//
#include <hip/hip_runtime.h>

// ---------------- problem constants ----------------
#define D_SZ 512
#define S_SZ 1024
#define H_SZ 2048
#define BS_SZ 32768
#define H_STEP 0.1f

typedef __attribute__((ext_vector_type(4))) float f32x4;
typedef __attribute__((ext_vector_type(8))) short s16x8;
typedef __attribute__((ext_vector_type(4))) unsigned short u16x4;
typedef unsigned short ushort_t;
typedef unsigned char u8;
typedef long long i64;

__device__ __forceinline__ ushort_t f2b(float f) {
    unsigned u = __float_as_uint(f);
    unsigned r = (u + 0x7FFFu + ((u >> 16) & 1u)) >> 16;
    return (ushort_t)r;
}
__device__ __forceinline__ float b2f(ushort_t b) {
    return __uint_as_float(((unsigned)b) << 16);
}

__device__ __forceinline__ void gload_lds16(const void* g, void* l) {
    __builtin_amdgcn_global_load_lds(
        (const __attribute__((address_space(1))) unsigned int*)g,
        (__attribute__((address_space(3))) unsigned int*)l, 16, 0, 0);
}

// ---------------- prep kernels ----------------
__global__ void prep_w1(const float* __restrict__ W1,
                        ushort_t* __restrict__ W1b) {
    int idx = blockIdx.x * 256 + threadIdx.x;   // over H*D = 1M
    W1b[idx] = f2b(W1[idx]);
}

// transpose W1 [2048h][512d] -> W1f8 [512d][2048h], fp8 e4m3, x8 scale
__global__ void prep_w1t8(const float* __restrict__ W1, u8* __restrict__ W1f8) {
    __shared__ float t[64][65];
    int hb = blockIdx.x >> 3;      // 0..31
    int db = blockIdx.x & 7;       // 0..7
    int tr = threadIdx.x >> 2;     // 0..63
    int tc = threadIdx.x & 3;      // 0..3
    const float* src = W1 + (size_t)(hb * 64 + tr) * D_SZ + db * 64 + tc * 16;
    #pragma unroll
    for (int j = 0; j < 16; j += 4) {
        f32x4 v = *(const f32x4*)(src + j);
        t[tr][tc * 16 + j + 0] = v[0];
        t[tr][tc * 16 + j + 1] = v[1];
        t[tr][tc * 16 + j + 2] = v[2];
        t[tr][tc * 16 + j + 3] = v[3];
    }
    __syncthreads();
    u8* dst = W1f8 + (size_t)(db * 64 + tr) * H_SZ + hb * 64 + tc * 16;
    #pragma unroll
    for (int j = 0; j < 16; j += 4) {
        int r = 0;
        r = __builtin_amdgcn_cvt_pk_fp8_f32(t[tc * 16 + j + 0][tr] * 8.0f,
                                            t[tc * 16 + j + 1][tr] * 8.0f, r, false);
        r = __builtin_amdgcn_cvt_pk_fp8_f32(t[tc * 16 + j + 2][tr] * 8.0f,
                                            t[tc * 16 + j + 3][tr] * 8.0f, r, true);
        *(int*)(dst + j) = r;
    }
}

__global__ void prep_mass(const float* __restrict__ logm,
                          float* __restrict__ inv_mass,
                          float* __restrict__ mass) {
    int s = blockIdx.x * 256 + threadIdx.x;
    if (s < S_SZ) {
        float lm = logm[s];
        mass[s] = expf(lm);
        inv_mass[s] = expf(-lm);
    }
}

// ---------------- embedding + p0 (q master is bf16 qb; p f32 in d_out) ----------------
__global__ void embed_kernel(const float* __restrict__ table,
                             const int* __restrict__ ids,
                             const float* __restrict__ mass,
                             float* __restrict__ p,
                             ushort_t* __restrict__ qb) {
    int i = blockIdx.x;          // row index in [0, BS)
    int t = threadIdx.x;
    int s = i & (S_SZ - 1);
    int id = ids[i];
    int idp = (s == 0) ? id : ids[i - 1];   // s==0: prev = self -> vel 0
    float mk = (id != 0) ? 1.f : 0.f;
    float ms = mass[s];
    int d0 = t * 4;

    f32x4 cur = {0.f, 0.f, 0.f, 0.f};
    f32x4 prv = {0.f, 0.f, 0.f, 0.f};
    if (id != 0)  cur = *(const f32x4*)(table + (size_t)id  * D_SZ + d0);
    if (idp != 0) prv = *(const f32x4*)(table + (size_t)idp * D_SZ + d0);

    size_t off = (size_t)i * D_SZ + d0;
    u16x4 cb;
    cb[0] = f2b(cur[0]); cb[1] = f2b(cur[1]); cb[2] = f2b(cur[2]); cb[3] = f2b(cur[3]);
    *(u16x4*)(qb + off) = cb;

    f32x4 pv;
    pv[0] = ms * (cur[0] - prv[0]) * mk;
    pv[1] = ms * (cur[1] - prv[1]) * mk;
    pv[2] = ms * (cur[2] - prv[2]) * mk;
    pv[3] = ms * (cur[3] - prv[3]) * mk;
    *(f32x4*)(p + off) = pv;
}

// =====================================================================
// force1 (bf16, R3-proven core): 256x256 tile, BK=32, 3 LDS bufs,
// counted vmcnt(4), T2 XOR-swizzle, setprio, XCD swizzle. 8 waves (2x4).
// C[r=h][c=i] = sum_k W1b[h,k]*qb[i,k].
// Epilogue: U[i,h] = fp8_e4m3(16 * sech2(C + b1[h]) * w2[h]).
// =====================================================================
__global__ __launch_bounds__(512, 2) void gemm_f1(
        const ushort_t* __restrict__ A,     // W1b [2048, 512]
        const ushort_t* __restrict__ B,     // qb  [BS, 512]
        const float* __restrict__ b1,
        const float* __restrict__ W2,
        u8* __restrict__ U) {
    constexpr int KLEN = 512;
    constexpr int NT = KLEN / 32;
    __shared__ __align__(16) ushort_t lA[3][256 * 32];
    __shared__ __align__(16) ushort_t lB[3][256 * 32];

    const int tid = threadIdx.x;
    const int lane = tid & 63, wid = tid >> 6;
    const int wm = wid >> 2, wn = wid & 3;
    const int lr = lane & 15, lk = lane >> 4;

    int wgid = ((int)blockIdx.x & 7) * 128 + ((int)blockIdx.x >> 3);  // nwg=1024
    int bxA = wgid & 7;          // 8 h-blocks
    int by  = wgid >> 3;         // 128 i-blocks
    const long a0 = (long)bxA * 256;
    const long b0 = (long)by * 256;

    const int r1  = tid >> 2;
    const int kc  = tid & 3;
    const int kcs = kc ^ ((r1 >> 1) & 3);
    const ushort_t* gA1 = A + (a0 + r1) * (long)KLEN + kcs * 8;
    const ushort_t* gA2 = gA1 + (long)128 * KLEN;
    const ushort_t* gB1 = B + (b0 + r1) * (long)KLEN + kcs * 8;
    const ushort_t* gB2 = gB1 + (long)128 * KLEN;
    const int ld1 = tid * 8;
    const int ld2 = (tid + 512) * 8;

#define STAGE_A(t) { int _b = (t) % 3;                         \
    gload_lds16(gA1 + (long)(t) * 32, &lA[_b][ld1]);           \
    gload_lds16(gA2 + (long)(t) * 32, &lA[_b][ld2]); }
#define STAGE_B(t) { int _b = (t) % 3;                         \
    gload_lds16(gB1 + (long)(t) * 32, &lB[_b][ld1]);           \
    gload_lds16(gB2 + (long)(t) * 32, &lB[_b][ld2]); }

    f32x4 acc[8][4];
    #pragma unroll
    for (int m = 0; m < 8; ++m)
        #pragma unroll
        for (int n = 0; n < 4; ++n)
            acc[m][n] = (f32x4){0.f, 0.f, 0.f, 0.f};

    const int lks8 = (lk ^ ((lr >> 1) & 3)) * 8;
    const int roA = (wm * 128 + lr) * 32 + lks8;
    const int roB = (wn * 64 + lr) * 32 + lks8;

    STAGE_A(0); STAGE_B(0);
    STAGE_A(1); STAGE_B(1);

    for (int t = 0; t < NT; ++t) {
        const int buf = t % 3;
        const ushort_t* bA = &lA[buf][0];
        const ushort_t* bB = &lB[buf][0];
        asm volatile("s_waitcnt vmcnt(4)" ::: "memory");
        __builtin_amdgcn_s_barrier();

        s16x8 av[4], bv[4];
        #pragma unroll
        for (int m = 0; m < 4; ++m) av[m] = *(const s16x8*)&bA[roA + m * 512];
        #pragma unroll
        for (int n = 0; n < 4; ++n) bv[n] = *(const s16x8*)&bB[roB + n * 512];
        if (t + 2 < NT) STAGE_A(t + 2);
        __builtin_amdgcn_s_setprio(1);
        #pragma unroll
        for (int m = 0; m < 4; ++m)
            #pragma unroll
            for (int n = 0; n < 4; ++n)
                acc[m][n] = __builtin_amdgcn_mfma_f32_16x16x32_bf16(av[m], bv[n], acc[m][n], 0, 0, 0);
        __builtin_amdgcn_s_setprio(0);
        __builtin_amdgcn_s_barrier();

        s16x8 av2[4];
        #pragma unroll
        for (int m = 0; m < 4; ++m) av2[m] = *(const s16x8*)&bA[roA + (m + 4) * 512];
        if (t + 2 < NT) STAGE_B(t + 2);
        __builtin_amdgcn_s_setprio(1);
        #pragma unroll
        for (int m = 0; m < 4; ++m)
            #pragma unroll
            for (int n = 0; n < 4; ++n)
                acc[m + 4][n] = __builtin_amdgcn_mfma_f32_16x16x32_bf16(av2[m], bv[n], acc[m + 4][n], 0, 0, 0);
        __builtin_amdgcn_s_setprio(0);
    }
#undef STAGE_A
#undef STAGE_B

    // epilogue: U[i,h] = fp8(16*sech2(C+b1)*w2)  (4 consecutive h per store)
    #pragma unroll
    for (int m = 0; m < 8; ++m) {
        long h0 = a0 + wm * 128 + m * 16 + lk * 4;
        f32x4 b1v = *(const f32x4*)(b1 + h0);
        f32x4 w2v = *(const f32x4*)(W2 + h0);
        #pragma unroll
        for (int n = 0; n < 4; ++n) {
            long i = b0 + wn * 64 + n * 16 + lr;
            float v[4];
            #pragma unroll
            for (int j = 0; j < 4; ++j) {
                float uu = acc[m][n][j] + b1v[j];
                // 16*sech^2(u)*w2 = 64*e/(1+e)^2*w2, e = exp(-2|u|)
                float e = __expf(-2.0f * fabsf(uu));
                float rc = 1.0f / (1.0f + e);
                v[j] = 64.0f * e * rc * rc * w2v[j];
            }
            int pk = 0;
            pk = __builtin_amdgcn_cvt_pk_fp8_f32(v[0], v[1], pk, false);
            pk = __builtin_amdgcn_cvt_pk_fp8_f32(v[2], v[3], pk, true);
            *(int*)(U + i * H_SZ + h0) = pk;
        }
    }
}

// =====================================================================
// force2 (fp8 x fp8): grid 512 = 2 d-halves x 256 i-tiles.
// Block = 256d x 128i, K=2048, BK=64. 8 waves = 4(d) x 2(i), 64d x 64i.
// Counted vmcnt(3). Epilogue (bf16-q-master leapfrog):
//   p(f32,RMW) -= (coef/128)*mask*G
//   if do_q: q = b2f(qb) + 0.1*p/m*mask -> qb (bf16); if wq also q f32 out.
// =====================================================================
__global__ __launch_bounds__(512, 2) void gemm_f2(
        const u8* __restrict__ W1f8,   // [512][2048]
        const u8* __restrict__ Uf8,    // [BS][2048]
        const int* __restrict__ ids,
        const float* __restrict__ inv_mass,
        float* __restrict__ qf,        // f32 q output (d_out), written when wq
        float* __restrict__ p,
        ushort_t* __restrict__ qb,
        float coef, int do_q, int wq) {
    __shared__ __align__(16) u8 lA[2][256 * 64];   // 32 KB
    __shared__ __align__(16) u8 lB[2][128 * 64];   // 16 KB

    const int tid = threadIdx.x;
    const int lane = tid & 63, wid = tid >> 6;
    const int wd = wid >> 1, wi = wid & 1;     // 4 (d) x 2 (i)
    const int lr = lane & 15, lk = lane >> 4;

    // bijective XCD swizzle, nwg=512; d-half fastest (shares U i-tile in L2)
    int wgid = ((int)blockIdx.x & 7) * 64 + ((int)blockIdx.x >> 3);
    const int  dh = wgid & 1;
    const long a0 = (long)dh * 256;             // d base
    const long b0 = (long)(wgid >> 1) * 128;    // i base

    const int r0  = tid >> 2;                   // 0..127
    const int kc  = tid & 3;
    const int kcs = kc ^ ((r0 >> 1) & 3);
    const u8* gA = W1f8 + (a0 + r0) * (long)H_SZ + kcs * 16;
    const u8* gB = Uf8 + (b0 + r0) * (long)H_SZ + kcs * 16;

#define STG(t) { int _b = (t) & 1; \
    gload_lds16(gA + (long)(t) * 64,               &lA[_b][tid * 16]); \
    gload_lds16(gA + 128L * H_SZ + (long)(t) * 64, &lA[_b][(tid + 512) * 16]); \
    gload_lds16(gB + (long)(t) * 64,               &lB[_b][tid * 16]); }

    f32x4 acc[4][4];
    #pragma unroll
    for (int m = 0; m < 4; ++m)
        #pragma unroll
        for (int n = 0; n < 4; ++n)
            acc[m][n] = (f32x4){0.f, 0.f, 0.f, 0.f};

    const int key = (lr >> 1) & 3;

    STG(0);
    const int NT = H_SZ / 64;   // 32
    for (int t = 0; t < NT; ++t) {
        if (t + 1 < NT) {
            STG(t + 1);
            asm volatile("s_waitcnt vmcnt(3)" ::: "memory");
        } else {
            asm volatile("s_waitcnt vmcnt(0)" ::: "memory");
        }
        __builtin_amdgcn_s_barrier();

        const u8* bA = &lA[t & 1][0];
        const u8* bB = &lB[t & 1][0];
        #pragma unroll
        for (int x = 0; x < 2; ++x) {
            // 8B fragment, k32-subtile x: slot c = x*2 + (lk>>1), XOR key
            const int so = (((x * 2 + (lk >> 1)) ^ key) * 16) + (lk & 1) * 8;
            i64 a[4], b[4];
            #pragma unroll
            for (int m = 0; m < 4; ++m)
                a[m] = *(const i64*)&bA[(wd * 64 + m * 16 + lr) * 64 + so];
            #pragma unroll
            for (int n = 0; n < 4; ++n)
                b[n] = *(const i64*)&bB[(wi * 64 + n * 16 + lr) * 64 + so];
            asm volatile("s_waitcnt lgkmcnt(0)" ::: "memory");
            __builtin_amdgcn_sched_barrier(0);
            __builtin_amdgcn_s_setprio(1);
            #pragma unroll
            for (int m = 0; m < 4; ++m)
                #pragma unroll
                for (int n = 0; n < 4; ++n)
                    acc[m][n] = __builtin_amdgcn_mfma_f32_16x16x32_fp8_fp8(a[m], b[n], acc[m][n], 0, 0, 0);
            __builtin_amdgcn_s_setprio(0);
        }
        __builtin_amdgcn_s_barrier();
    }
#undef STG

    // epilogue: p -= (coef/128)*mask*G ; q = qb + 0.1*p/m*mask -> qb (+ f32 out at wq)
    const float cs = coef * (1.0f / 128.0f);
    #pragma unroll
    for (int n = 0; n < 4; ++n) {
        long i = b0 + wi * 64 + n * 16 + lr;
        int id = ids[i];
        float cm = (id != 0) ? cs : 0.f;
        float hm = (id != 0) ? H_STEP : 0.f;
        float im = inv_mass[(int)(i & (S_SZ - 1))];
        #pragma unroll
        for (int m = 0; m < 4; ++m) {
            long d0 = a0 + wd * 64 + m * 16 + lk * 4;
            size_t off = (size_t)i * D_SZ + d0;
            f32x4 pv = *(const f32x4*)(p + off);
            #pragma unroll
            for (int j = 0; j < 4; ++j)
                pv[j] -= cm * acc[m][n][j];
            *(f32x4*)(p + off) = pv;
            if (do_q) {
                u16x4 qo = *(const u16x4*)(qb + off);
                f32x4 qv;
                u16x4 qn;
                #pragma unroll
                for (int j = 0; j < 4; ++j) {
                    qv[j] = b2f(qo[j]) + hm * pv[j] * im;
                    qn[j] = f2b(qv[j]);
                }
                *(u16x4*)(qb + off) = qn;
                if (wq) *(f32x4*)(qf + off) = qv;
            }
        }
    }
}

// ---------------- host launch ----------------
extern "C" void kernel_launch(void* const* d_in, const int* in_sizes, int n_in,
                              void* d_out, int out_size, void* d_ws, size_t ws_size,
                              hipStream_t stream) {
    const float* table = (const float*)d_in[0];
    const float* logm  = (const float*)d_in[1];
    const float* W1    = (const float*)d_in[2];
    const float* b1    = (const float*)d_in[3];
    const float* W2    = (const float*)d_in[4];
    // d_in[5] = b2, unused by the force (only shifts the potential value)
    const int*   ids   = (const int*)d_in[6];

    float* qf = (float*)d_out;                      // [BS, D] f32 q (written at j=4)
    float* p  = qf + (size_t)BS_SZ * D_SZ;          // [BS, D] f32 p (master, RMW)

    char* ws = (char*)d_ws;
    size_t o = 0;
    ushort_t* qb  = (ushort_t*)(ws + o); o += (size_t)BS_SZ * D_SZ * 2;   // 32 MB (bf16 q master)
    u8* Uf8       = (u8*)(ws + o);       o += (size_t)BS_SZ * H_SZ;       // 64 MB
    ushort_t* W1b = (ushort_t*)(ws + o); o += (size_t)H_SZ * D_SZ * 2;    // 2 MB
    u8* W1f8      = (u8*)(ws + o);       o += (size_t)D_SZ * H_SZ;        // 1 MB
    float* inv_mass = (float*)(ws + o);  o += S_SZ * 4;
    float* mass     = (float*)(ws + o);  o += S_SZ * 4;

    prep_w1<<<(H_SZ * D_SZ) / 256, 256, 0, stream>>>(W1, W1b);
    prep_w1t8<<<256, 256, 0, stream>>>(W1, W1f8);
    prep_mass<<<(S_SZ + 255) / 256, 256, 0, stream>>>(logm, inv_mass, mass);
    embed_kernel<<<BS_SZ, 128, 0, stream>>>(table, ids, mass, p, qb);

    // 6 distinct force evals: j=0 -> +0.05*f(q0); j=1..4 -> +0.1*f(qj); j=5 -> +0.05*f(q5)
    for (int j = 0; j < 6; ++j) {
        gemm_f1<<<1024, 512, 0, stream>>>(W1b, qb, b1, W2, Uf8);
        float coef = (j == 0 || j == 5) ? 0.05f : 0.1f;
        gemm_f2<<<512, 512, 0, stream>>>(
            W1f8, Uf8, ids, inv_mass, qf, p, qb, coef, (j < 5) ? 1 : 0, (j == 4) ? 1 : 0);
    }
}

// Round 13
// 1109.117 us; speedup vs baseline: 1.4884x; 1.0163x over previous
//
#include <hip/hip_runtime.h>

// ---------------- problem constants ----------------
#define D_SZ 512
#define S_SZ 1024
#define H_SZ 2048
#define BS_SZ 32768
#define H_STEP 0.1f

typedef __attribute__((ext_vector_type(4))) float f32x4;
typedef __attribute__((ext_vector_type(8))) short s16x8;
typedef __attribute__((ext_vector_type(4))) unsigned short u16x4;
typedef unsigned short ushort_t;
typedef unsigned char u8;
typedef long long i64;

__device__ __forceinline__ ushort_t f2b(float f) {
    unsigned u = __float_as_uint(f);
    unsigned r = (u + 0x7FFFu + ((u >> 16) & 1u)) >> 16;
    return (ushort_t)r;
}
__device__ __forceinline__ float b2f(ushort_t b) {
    return __uint_as_float(((unsigned)b) << 16);
}

__device__ __forceinline__ void gload_lds16(const void* g, void* l) {
    __builtin_amdgcn_global_load_lds(
        (const __attribute__((address_space(1))) unsigned int*)g,
        (__attribute__((address_space(3))) unsigned int*)l, 16, 0, 0);
}

// ---------------- prep kernels ----------------
__global__ void prep_w1(const float* __restrict__ W1,
                        ushort_t* __restrict__ W1b) {
    int idx = blockIdx.x * 256 + threadIdx.x;   // over H*D = 1M
    W1b[idx] = f2b(W1[idx]);
}

// transpose W1 [2048h][512d] -> W1f8 [512d][2048h], fp8 e4m3, x8 scale
__global__ void prep_w1t8(const float* __restrict__ W1, u8* __restrict__ W1f8) {
    __shared__ float t[64][65];
    int hb = blockIdx.x >> 3;      // 0..31
    int db = blockIdx.x & 7;       // 0..7
    int tr = threadIdx.x >> 2;     // 0..63
    int tc = threadIdx.x & 3;      // 0..3
    const float* src = W1 + (size_t)(hb * 64 + tr) * D_SZ + db * 64 + tc * 16;
    #pragma unroll
    for (int j = 0; j < 16; j += 4) {
        f32x4 v = *(const f32x4*)(src + j);
        t[tr][tc * 16 + j + 0] = v[0];
        t[tr][tc * 16 + j + 1] = v[1];
        t[tr][tc * 16 + j + 2] = v[2];
        t[tr][tc * 16 + j + 3] = v[3];
    }
    __syncthreads();
    u8* dst = W1f8 + (size_t)(db * 64 + tr) * H_SZ + hb * 64 + tc * 16;
    #pragma unroll
    for (int j = 0; j < 16; j += 4) {
        int r = 0;
        r = __builtin_amdgcn_cvt_pk_fp8_f32(t[tc * 16 + j + 0][tr] * 8.0f,
                                            t[tc * 16 + j + 1][tr] * 8.0f, r, false);
        r = __builtin_amdgcn_cvt_pk_fp8_f32(t[tc * 16 + j + 2][tr] * 8.0f,
                                            t[tc * 16 + j + 3][tr] * 8.0f, r, true);
        *(int*)(dst + j) = r;
    }
}

__global__ void prep_mass(const float* __restrict__ logm,
                          float* __restrict__ inv_mass,
                          float* __restrict__ mass) {
    int s = blockIdx.x * 256 + threadIdx.x;
    if (s < S_SZ) {
        float lm = logm[s];
        mass[s] = expf(lm);
        inv_mass[s] = expf(-lm);
    }
}

// ---------------- embedding + p0 (q master is bf16 qb; p f32 in d_out) ----------------
__global__ void embed_kernel(const float* __restrict__ table,
                             const int* __restrict__ ids,
                             const float* __restrict__ mass,
                             float* __restrict__ p,
                             ushort_t* __restrict__ qb) {
    int i = blockIdx.x;          // row index in [0, BS)
    int t = threadIdx.x;
    int s = i & (S_SZ - 1);
    int id = ids[i];
    int idp = (s == 0) ? id : ids[i - 1];   // s==0: prev = self -> vel 0
    float mk = (id != 0) ? 1.f : 0.f;
    float ms = mass[s];
    int d0 = t * 4;

    f32x4 cur = {0.f, 0.f, 0.f, 0.f};
    f32x4 prv = {0.f, 0.f, 0.f, 0.f};
    if (id != 0)  cur = *(const f32x4*)(table + (size_t)id  * D_SZ + d0);
    if (idp != 0) prv = *(const f32x4*)(table + (size_t)idp * D_SZ + d0);

    size_t off = (size_t)i * D_SZ + d0;
    u16x4 cb;
    cb[0] = f2b(cur[0]); cb[1] = f2b(cur[1]); cb[2] = f2b(cur[2]); cb[3] = f2b(cur[3]);
    *(u16x4*)(qb + off) = cb;

    f32x4 pv;
    pv[0] = ms * (cur[0] - prv[0]) * mk;
    pv[1] = ms * (cur[1] - prv[1]) * mk;
    pv[2] = ms * (cur[2] - prv[2]) * mk;
    pv[3] = ms * (cur[3] - prv[3]) * mk;
    *(f32x4*)(p + off) = pv;
}

// =====================================================================
// force1 v3 (bf16): 256x256 tile, 1024 threads = 16 waves (4h x 4i),
// wave tile 64x64, acc[4][4] (~116 VGPR -> 4 waves/SIMD). BK=32,
// 3 LDS bufs (96 KB), 2-ahead counted vmcnt(2), T2 XOR-swizzle,
// setprio, XCD swizzle. C[r=h][c=i] = sum_k W1b[h,k]*qb[i,k].
// Epilogue: U[i,h] = fp8_e4m3(16 * sech2(C + b1[h]) * w2[h]).
// =====================================================================
__global__ __launch_bounds__(1024, 4) void gemm_f1(
        const ushort_t* __restrict__ A,     // W1b [2048, 512]
        const ushort_t* __restrict__ B,     // qb  [BS, 512]
        const float* __restrict__ b1,
        const float* __restrict__ W2,
        u8* __restrict__ U) {
    constexpr int KLEN = 512;
    constexpr int NT = KLEN / 32;           // 16
    __shared__ __align__(16) ushort_t lA[3][256 * 32];   // 48 KB
    __shared__ __align__(16) ushort_t lB[3][256 * 32];   // 48 KB

    const int tid = threadIdx.x;
    const int lane = tid & 63, wid = tid >> 6;
    const int wg = wid >> 2, wn = wid & 3;  // 4 (h) x 4 (i) wave grid
    const int lr = lane & 15, lk = lane >> 4;

    int wgid = ((int)blockIdx.x & 7) * 128 + ((int)blockIdx.x >> 3);  // nwg=1024
    int bxA = wgid & 7;          // 8 h-blocks
    int by  = wgid >> 3;         // 128 i-blocks
    const long a0 = (long)bxA * 256;
    const long b0 = (long)by * 256;

    // staging: 1 16B-chunk per thread per array; row r0 = tid>>2, slot kc = tid&3
    const int r0  = tid >> 2;               // 0..255
    const int kc  = tid & 3;
    const int kcs = kc ^ ((r0 >> 1) & 3);   // T2 pre-swizzled source slot
    const ushort_t* gA = A + (a0 + r0) * (long)KLEN + kcs * 8;
    const ushort_t* gB = B + (b0 + r0) * (long)KLEN + kcs * 8;

#define STAGE(t) { int _b = (t) % 3;                          \
    gload_lds16(gA + (long)(t) * 32, &lA[_b][tid * 8]);       \
    gload_lds16(gB + (long)(t) * 32, &lB[_b][tid * 8]); }

    f32x4 acc[4][4];
    #pragma unroll
    for (int m = 0; m < 4; ++m)
        #pragma unroll
        for (int n = 0; n < 4; ++n)
            acc[m][n] = (f32x4){0.f, 0.f, 0.f, 0.f};

    const int lks8 = (lk ^ ((lr >> 1) & 3)) * 8;
    const int roA = (wg * 64 + lr) * 32 + lks8;   // + m*512 per 16-row frag
    const int roB = (wn * 64 + lr) * 32 + lks8;   // + n*512

    STAGE(0);
    STAGE(1);

    for (int t = 0; t < NT; ++t) {
        const int buf = t % 3;
        const ushort_t* bA = &lA[buf][0];
        const ushort_t* bB = &lB[buf][0];
        if (t < NT - 1) asm volatile("s_waitcnt vmcnt(2)" ::: "memory");
        else           asm volatile("s_waitcnt vmcnt(0)" ::: "memory");
        __builtin_amdgcn_s_barrier();

        s16x8 av[4], bv[4];
        #pragma unroll
        for (int m = 0; m < 4; ++m) av[m] = *(const s16x8*)&bA[roA + m * 512];
        #pragma unroll
        for (int n = 0; n < 4; ++n) bv[n] = *(const s16x8*)&bB[roB + n * 512];
        asm volatile("s_waitcnt lgkmcnt(0)" ::: "memory");
        __builtin_amdgcn_sched_barrier(0);
        __builtin_amdgcn_s_setprio(1);
        #pragma unroll
        for (int m = 0; m < 4; ++m)
            #pragma unroll
            for (int n = 0; n < 4; ++n)
                acc[m][n] = __builtin_amdgcn_mfma_f32_16x16x32_bf16(av[m], bv[n], acc[m][n], 0, 0, 0);
        __builtin_amdgcn_s_setprio(0);
        __builtin_amdgcn_s_barrier();
        if (t + 2 < NT) STAGE(t + 2);
    }
#undef STAGE

    // epilogue: U[i,h] = fp8(16*sech2(C+b1)*w2)  (4 consecutive h per store)
    #pragma unroll
    for (int m = 0; m < 4; ++m) {
        long h0 = a0 + wg * 64 + m * 16 + lk * 4;
        f32x4 b1v = *(const f32x4*)(b1 + h0);
        f32x4 w2v = *(const f32x4*)(W2 + h0);
        #pragma unroll
        for (int n = 0; n < 4; ++n) {
            long i = b0 + wn * 64 + n * 16 + lr;
            float v[4];
            #pragma unroll
            for (int j = 0; j < 4; ++j) {
                float uu = acc[m][n][j] + b1v[j];
                // 16*sech^2(u)*w2 = 64*e/(1+e)^2*w2, e = exp(-2|u|)
                float e = __expf(-2.0f * fabsf(uu));
                float rc = 1.0f / (1.0f + e);
                v[j] = 64.0f * e * rc * rc * w2v[j];
            }
            int pk = 0;
            pk = __builtin_amdgcn_cvt_pk_fp8_f32(v[0], v[1], pk, false);
            pk = __builtin_amdgcn_cvt_pk_fp8_f32(v[2], v[3], pk, true);
            *(int*)(U + i * H_SZ + h0) = pk;
        }
    }
}

// =====================================================================
// force2 (fp8 x fp8): grid 512 = 2 d-halves x 256 i-tiles.
// Block = 256d x 128i, K=2048, BK=64. 8 waves = 4(d) x 2(i), 64d x 64i.
// Counted vmcnt(3). Epilogue (bf16-q-master leapfrog):
//   p(f32,RMW) -= (coef/128)*mask*G
//   if do_q: q = b2f(qb) + 0.1*p/m*mask -> qb (bf16); if wq also q f32 out.
// =====================================================================
__global__ __launch_bounds__(512, 2) void gemm_f2(
        const u8* __restrict__ W1f8,   // [512][2048]
        const u8* __restrict__ Uf8,    // [BS][2048]
        const int* __restrict__ ids,
        const float* __restrict__ inv_mass,
        float* __restrict__ qf,        // f32 q output (d_out), written when wq
        float* __restrict__ p,
        ushort_t* __restrict__ qb,
        float coef, int do_q, int wq) {
    __shared__ __align__(16) u8 lA[2][256 * 64];   // 32 KB
    __shared__ __align__(16) u8 lB[2][128 * 64];   // 16 KB

    const int tid = threadIdx.x;
    const int lane = tid & 63, wid = tid >> 6;
    const int wd = wid >> 1, wi = wid & 1;     // 4 (d) x 2 (i)
    const int lr = lane & 15, lk = lane >> 4;

    // bijective XCD swizzle, nwg=512; d-half fastest (shares U i-tile in L2)
    int wgid = ((int)blockIdx.x & 7) * 64 + ((int)blockIdx.x >> 3);
    const int  dh = wgid & 1;
    const long a0 = (long)dh * 256;             // d base
    const long b0 = (long)(wgid >> 1) * 128;    // i base

    const int r0  = tid >> 2;                   // 0..127
    const int kc  = tid & 3;
    const int kcs = kc ^ ((r0 >> 1) & 3);
    const u8* gA = W1f8 + (a0 + r0) * (long)H_SZ + kcs * 16;
    const u8* gB = Uf8 + (b0 + r0) * (long)H_SZ + kcs * 16;

#define STG(t) { int _b = (t) & 1; \
    gload_lds16(gA + (long)(t) * 64,               &lA[_b][tid * 16]); \
    gload_lds16(gA + 128L * H_SZ + (long)(t) * 64, &lA[_b][(tid + 512) * 16]); \
    gload_lds16(gB + (long)(t) * 64,               &lB[_b][tid * 16]); }

    f32x4 acc[4][4];
    #pragma unroll
    for (int m = 0; m < 4; ++m)
        #pragma unroll
        for (int n = 0; n < 4; ++n)
            acc[m][n] = (f32x4){0.f, 0.f, 0.f, 0.f};

    const int key = (lr >> 1) & 3;

    STG(0);
    const int NT = H_SZ / 64;   // 32
    for (int t = 0; t < NT; ++t) {
        if (t + 1 < NT) {
            STG(t + 1);
            asm volatile("s_waitcnt vmcnt(3)" ::: "memory");
        } else {
            asm volatile("s_waitcnt vmcnt(0)" ::: "memory");
        }
        __builtin_amdgcn_s_barrier();

        const u8* bA = &lA[t & 1][0];
        const u8* bB = &lB[t & 1][0];
        #pragma unroll
        for (int x = 0; x < 2; ++x) {
            // 8B fragment, k32-subtile x: slot c = x*2 + (lk>>1), XOR key
            const int so = (((x * 2 + (lk >> 1)) ^ key) * 16) + (lk & 1) * 8;
            i64 a[4], b[4];
            #pragma unroll
            for (int m = 0; m < 4; ++m)
                a[m] = *(const i64*)&bA[(wd * 64 + m * 16 + lr) * 64 + so];
            #pragma unroll
            for (int n = 0; n < 4; ++n)
                b[n] = *(const i64*)&bB[(wi * 64 + n * 16 + lr) * 64 + so];
            asm volatile("s_waitcnt lgkmcnt(0)" ::: "memory");
            __builtin_amdgcn_sched_barrier(0);
            __builtin_amdgcn_s_setprio(1);
            #pragma unroll
            for (int m = 0; m < 4; ++m)
                #pragma unroll
                for (int n = 0; n < 4; ++n)
                    acc[m][n] = __builtin_amdgcn_mfma_f32_16x16x32_fp8_fp8(a[m], b[n], acc[m][n], 0, 0, 0);
            __builtin_amdgcn_s_setprio(0);
        }
        __builtin_amdgcn_s_barrier();
    }
#undef STG

    // epilogue: p -= (coef/128)*mask*G ; q = qb + 0.1*p/m*mask -> qb (+ f32 out at wq)
    const float cs = coef * (1.0f / 128.0f);
    #pragma unroll
    for (int n = 0; n < 4; ++n) {
        long i = b0 + wi * 64 + n * 16 + lr;
        int id = ids[i];
        float cm = (id != 0) ? cs : 0.f;
        float hm = (id != 0) ? H_STEP : 0.f;
        float im = inv_mass[(int)(i & (S_SZ - 1))];
        #pragma unroll
        for (int m = 0; m < 4; ++m) {
            long d0 = a0 + wd * 64 + m * 16 + lk * 4;
            size_t off = (size_t)i * D_SZ + d0;
            f32x4 pv = *(const f32x4*)(p + off);
            #pragma unroll
            for (int j = 0; j < 4; ++j)
                pv[j] -= cm * acc[m][n][j];
            *(f32x4*)(p + off) = pv;
            if (do_q) {
                u16x4 qo = *(const u16x4*)(qb + off);
                f32x4 qv;
                u16x4 qn;
                #pragma unroll
                for (int j = 0; j < 4; ++j) {
                    qv[j] = b2f(qo[j]) + hm * pv[j] * im;
                    qn[j] = f2b(qv[j]);
                }
                *(u16x4*)(qb + off) = qn;
                if (wq) *(f32x4*)(qf + off) = qv;
            }
        }
    }
}

// ---------------- host launch ----------------
extern "C" void kernel_launch(void* const* d_in, const int* in_sizes, int n_in,
                              void* d_out, int out_size, void* d_ws, size_t ws_size,
                              hipStream_t stream) {
    const float* table = (const float*)d_in[0];
    const float* logm  = (const float*)d_in[1];
    const float* W1    = (const float*)d_in[2];
    const float* b1    = (const float*)d_in[3];
    const float* W2    = (const float*)d_in[4];
    // d_in[5] = b2, unused by the force (only shifts the potential value)
    const int*   ids   = (const int*)d_in[6];

    float* qf = (float*)d_out;                      // [BS, D] f32 q (written at j=4)
    float* p  = qf + (size_t)BS_SZ * D_SZ;          // [BS, D] f32 p (master, RMW)

    char* ws = (char*)d_ws;
    size_t o = 0;
    ushort_t* qb  = (ushort_t*)(ws + o); o += (size_t)BS_SZ * D_SZ * 2;   // 32 MB (bf16 q master)
    u8* Uf8       = (u8*)(ws + o);       o += (size_t)BS_SZ * H_SZ;       // 64 MB
    ushort_t* W1b = (ushort_t*)(ws + o); o += (size_t)H_SZ * D_SZ * 2;    // 2 MB
    u8* W1f8      = (u8*)(ws + o);       o += (size_t)D_SZ * H_SZ;        // 1 MB
    float* inv_mass = (float*)(ws + o);  o += S_SZ * 4;
    float* mass     = (float*)(ws + o);  o += S_SZ * 4;

    prep_w1<<<(H_SZ * D_SZ) / 256, 256, 0, stream>>>(W1, W1b);
    prep_w1t8<<<256, 256, 0, stream>>>(W1, W1f8);
    prep_mass<<<(S_SZ + 255) / 256, 256, 0, stream>>>(logm, inv_mass, mass);
    embed_kernel<<<BS_SZ, 128, 0, stream>>>(table, ids, mass, p, qb);

    // 6 distinct force evals: j=0 -> +0.05*f(q0); j=1..4 -> +0.1*f(qj); j=5 -> +0.05*f(q5)
    for (int j = 0; j < 6; ++j) {
        gemm_f1<<<1024, 1024, 0, stream>>>(W1b, qb, b1, W2, Uf8);
        float coef = (j == 0 || j == 5) ? 0.05f : 0.1f;
        gemm_f2<<<512, 512, 0, stream>>>(
            W1f8, Uf8, ids, inv_mass, qf, p, qb, coef, (j < 5) ? 1 : 0, (j == 4) ? 1 : 0);
    }
}

// Round 14
// 1092.659 us; speedup vs baseline: 1.5108x; 1.0151x over previous
//
#include <hip/hip_runtime.h>

// ---------------- problem constants ----------------
#define D_SZ 512
#define S_SZ 1024
#define H_SZ 2048
#define BS_SZ 32768
#define H_STEP 0.1f

typedef __attribute__((ext_vector_type(4))) float f32x4;
typedef __attribute__((ext_vector_type(8))) short s16x8;
typedef __attribute__((ext_vector_type(4))) unsigned short u16x4;
typedef unsigned short ushort_t;
typedef unsigned char u8;
typedef long long i64;

__device__ __forceinline__ ushort_t f2b(float f) {
    unsigned u = __float_as_uint(f);
    unsigned r = (u + 0x7FFFu + ((u >> 16) & 1u)) >> 16;
    return (ushort_t)r;
}
__device__ __forceinline__ float b2f(ushort_t b) {
    return __uint_as_float(((unsigned)b) << 16);
}

__device__ __forceinline__ void gload_lds16(const void* g, void* l) {
    __builtin_amdgcn_global_load_lds(
        (const __attribute__((address_space(1))) unsigned int*)g,
        (__attribute__((address_space(3))) unsigned int*)l, 16, 0, 0);
}

// ---------------- prep kernels ----------------
// W1 row-major fp8 (x8 scale): [2048h][512d]
__global__ void prep_w1r8(const float* __restrict__ W1, u8* __restrict__ W1f8r) {
    int idx4 = (blockIdx.x * 256 + threadIdx.x) * 4;   // over H*D = 1M
    f32x4 v = *(const f32x4*)(W1 + idx4);
    int r = 0;
    r = __builtin_amdgcn_cvt_pk_fp8_f32(v[0] * 8.0f, v[1] * 8.0f, r, false);
    r = __builtin_amdgcn_cvt_pk_fp8_f32(v[2] * 8.0f, v[3] * 8.0f, r, true);
    *(int*)(W1f8r + idx4) = r;
}

// transpose W1 [2048h][512d] -> W1f8 [512d][2048h], fp8 e4m3, x8 scale
__global__ void prep_w1t8(const float* __restrict__ W1, u8* __restrict__ W1f8) {
    __shared__ float t[64][65];
    int hb = blockIdx.x >> 3;      // 0..31
    int db = blockIdx.x & 7;       // 0..7
    int tr = threadIdx.x >> 2;     // 0..63
    int tc = threadIdx.x & 3;      // 0..3
    const float* src = W1 + (size_t)(hb * 64 + tr) * D_SZ + db * 64 + tc * 16;
    #pragma unroll
    for (int j = 0; j < 16; j += 4) {
        f32x4 v = *(const f32x4*)(src + j);
        t[tr][tc * 16 + j + 0] = v[0];
        t[tr][tc * 16 + j + 1] = v[1];
        t[tr][tc * 16 + j + 2] = v[2];
        t[tr][tc * 16 + j + 3] = v[3];
    }
    __syncthreads();
    u8* dst = W1f8 + (size_t)(db * 64 + tr) * H_SZ + hb * 64 + tc * 16;
    #pragma unroll
    for (int j = 0; j < 16; j += 4) {
        int r = 0;
        r = __builtin_amdgcn_cvt_pk_fp8_f32(t[tc * 16 + j + 0][tr] * 8.0f,
                                            t[tc * 16 + j + 1][tr] * 8.0f, r, false);
        r = __builtin_amdgcn_cvt_pk_fp8_f32(t[tc * 16 + j + 2][tr] * 8.0f,
                                            t[tc * 16 + j + 3][tr] * 8.0f, r, true);
        *(int*)(dst + j) = r;
    }
}

__global__ void prep_mass(const float* __restrict__ logm,
                          float* __restrict__ inv_mass,
                          float* __restrict__ mass) {
    int s = blockIdx.x * 256 + threadIdx.x;
    if (s < S_SZ) {
        float lm = logm[s];
        mass[s] = expf(lm);
        inv_mass[s] = expf(-lm);
    }
}

// ---------------- embedding + p0 (q: bf16 master qb + fp8 shadow q8) ----------------
__global__ void embed_kernel(const float* __restrict__ table,
                             const int* __restrict__ ids,
                             const float* __restrict__ mass,
                             float* __restrict__ p,
                             ushort_t* __restrict__ qb,
                             u8* __restrict__ q8) {
    int i = blockIdx.x;          // row index in [0, BS)
    int t = threadIdx.x;
    int s = i & (S_SZ - 1);
    int id = ids[i];
    int idp = (s == 0) ? id : ids[i - 1];   // s==0: prev = self -> vel 0
    float mk = (id != 0) ? 1.f : 0.f;
    float ms = mass[s];
    int d0 = t * 4;

    f32x4 cur = {0.f, 0.f, 0.f, 0.f};
    f32x4 prv = {0.f, 0.f, 0.f, 0.f};
    if (id != 0)  cur = *(const f32x4*)(table + (size_t)id  * D_SZ + d0);
    if (idp != 0) prv = *(const f32x4*)(table + (size_t)idp * D_SZ + d0);

    size_t off = (size_t)i * D_SZ + d0;
    u16x4 cb;
    cb[0] = f2b(cur[0]); cb[1] = f2b(cur[1]); cb[2] = f2b(cur[2]); cb[3] = f2b(cur[3]);
    *(u16x4*)(qb + off) = cb;
    int pk8 = 0;
    pk8 = __builtin_amdgcn_cvt_pk_fp8_f32(cur[0] * 32.f, cur[1] * 32.f, pk8, false);
    pk8 = __builtin_amdgcn_cvt_pk_fp8_f32(cur[2] * 32.f, cur[3] * 32.f, pk8, true);
    *(int*)(q8 + off) = pk8;

    f32x4 pv;
    pv[0] = ms * (cur[0] - prv[0]) * mk;
    pv[1] = ms * (cur[1] - prv[1]) * mk;
    pv[2] = ms * (cur[2] - prv[2]) * mk;
    pv[3] = ms * (cur[3] - prv[3]) * mk;
    *(f32x4*)(p + off) = pv;
}

// =====================================================================
// force1 v4 (fp8 x fp8): 256x256 tile, 1024 threads = 16 waves (4h x 4i),
// wave tile 64x64, acc[4][4]. K=512, BK=64 (8 tiles), 3 LDS bufs (96 KB),
// 2-ahead counted vmcnt(2), T2 XOR-swizzle (16B slots), setprio, XCD swz.
// A = W1f8r (x8) rows h; B = q8 (x32) rows i -> acc = 256*u.
// Epilogue: U[i,h] = fp8_e4m3(16 * sech2(u) * w2[h]).
// =====================================================================
__global__ __launch_bounds__(1024, 4) void gemm_f1(
        const u8* __restrict__ A,      // W1f8r [2048, 512]
        const u8* __restrict__ B,      // q8    [BS, 512]
        const float* __restrict__ b1,
        const float* __restrict__ W2,
        u8* __restrict__ U) {
    constexpr int KLEN = 512;
    constexpr int NT = KLEN / 64;           // 8
    __shared__ __align__(16) u8 lA[3][256 * 64];   // 48 KB
    __shared__ __align__(16) u8 lB[3][256 * 64];   // 48 KB

    const int tid = threadIdx.x;
    const int lane = tid & 63, wid = tid >> 6;
    const int wg = wid >> 2, wn = wid & 3;  // 4 (h) x 4 (i) wave grid
    const int lr = lane & 15, lk = lane >> 4;

    int wgid = ((int)blockIdx.x & 7) * 128 + ((int)blockIdx.x >> 3);  // nwg=1024
    int bxA = wgid & 7;          // 8 h-blocks
    int by  = wgid >> 3;         // 128 i-blocks
    const long a0 = (long)bxA * 256;
    const long b0 = (long)by * 256;

    // staging: 1 16B-chunk per thread per array; row r0 = tid>>2 (0..255),
    // 16B-slot kc = tid&3 of the 64B row-chunk; source slot kcs = kc^((r0>>1)&3)
    const int r0  = tid >> 2;
    const int kc  = tid & 3;
    const int kcs = kc ^ ((r0 >> 1) & 3);
    const u8* gA = A + (a0 + r0) * (long)KLEN + kcs * 16;
    const u8* gB = B + (b0 + r0) * (long)KLEN + kcs * 16;

#define STAGE(t) { int _b = (t) % 3;                           \
    gload_lds16(gA + (long)(t) * 64, &lA[_b][tid * 16]);       \
    gload_lds16(gB + (long)(t) * 64, &lB[_b][tid * 16]); }

    f32x4 acc[4][4];
    #pragma unroll
    for (int m = 0; m < 4; ++m)
        #pragma unroll
        for (int n = 0; n < 4; ++n)
            acc[m][n] = (f32x4){0.f, 0.f, 0.f, 0.f};

    const int key = (lr >> 1) & 3;

    STAGE(0);
    STAGE(1);

    for (int t = 0; t < NT; ++t) {
        const int buf = t % 3;
        const u8* bA = &lA[buf][0];
        const u8* bB = &lB[buf][0];
        if (t < NT - 1) asm volatile("s_waitcnt vmcnt(2)" ::: "memory");
        else           asm volatile("s_waitcnt vmcnt(0)" ::: "memory");
        __builtin_amdgcn_s_barrier();

        #pragma unroll
        for (int x = 0; x < 2; ++x) {
            // 8B fragment, k32-subtile x: 16B-slot c = x*2 + (lk>>1), XOR key
            const int so = (((x * 2 + (lk >> 1)) ^ key) * 16) + (lk & 1) * 8;
            i64 a[4], b[4];
            #pragma unroll
            for (int m = 0; m < 4; ++m)
                a[m] = *(const i64*)&bA[(wg * 64 + m * 16 + lr) * 64 + so];
            #pragma unroll
            for (int n = 0; n < 4; ++n)
                b[n] = *(const i64*)&bB[(wn * 64 + n * 16 + lr) * 64 + so];
            asm volatile("s_waitcnt lgkmcnt(0)" ::: "memory");
            __builtin_amdgcn_sched_barrier(0);
            __builtin_amdgcn_s_setprio(1);
            #pragma unroll
            for (int m = 0; m < 4; ++m)
                #pragma unroll
                for (int n = 0; n < 4; ++n)
                    acc[m][n] = __builtin_amdgcn_mfma_f32_16x16x32_fp8_fp8(a[m], b[n], acc[m][n], 0, 0, 0);
            __builtin_amdgcn_s_setprio(0);
        }
        __builtin_amdgcn_s_barrier();
        if (t + 2 < NT) STAGE(t + 2);
    }
#undef STAGE

    // epilogue: u = acc/256; U[i,h] = fp8(16*sech2(u)*w2)
    #pragma unroll
    for (int m = 0; m < 4; ++m) {
        long h0 = a0 + wg * 64 + m * 16 + lk * 4;
        f32x4 b1v = *(const f32x4*)(b1 + h0);
        f32x4 w2v = *(const f32x4*)(W2 + h0);
        #pragma unroll
        for (int n = 0; n < 4; ++n) {
            long i = b0 + wn * 64 + n * 16 + lr;
            float v[4];
            #pragma unroll
            for (int j = 0; j < 4; ++j) {
                float uu = acc[m][n][j] * 0.00390625f + b1v[j];
                // 16*sech^2(u)*w2 = 64*e/(1+e)^2*w2, e = exp(-2|u|)
                float e = __expf(-2.0f * fabsf(uu));
                float rc = 1.0f / (1.0f + e);
                v[j] = 64.0f * e * rc * rc * w2v[j];
            }
            int pk = 0;
            pk = __builtin_amdgcn_cvt_pk_fp8_f32(v[0], v[1], pk, false);
            pk = __builtin_amdgcn_cvt_pk_fp8_f32(v[2], v[3], pk, true);
            *(int*)(U + i * H_SZ + h0) = pk;
        }
    }
}

// =====================================================================
// force2 (fp8 x fp8): grid 512 = 2 d-halves x 256 i-tiles.
// Block = 256d x 128i, K=2048, BK=64. 8 waves = 4(d) x 2(i), 64d x 64i.
// Counted vmcnt(3). Epilogue (bf16-q-master leapfrog):
//   p(f32,RMW) -= (coef/128)*mask*G
//   if do_q: q = b2f(qb) + 0.1*p/m*mask -> qb(bf16) + q8(fp8 x32);
//            if wq also q f32 out.
// =====================================================================
__global__ __launch_bounds__(512, 2) void gemm_f2(
        const u8* __restrict__ W1f8,   // [512][2048]
        const u8* __restrict__ Uf8,    // [BS][2048]
        const int* __restrict__ ids,
        const float* __restrict__ inv_mass,
        float* __restrict__ qf,        // f32 q output (d_out), written when wq
        float* __restrict__ p,
        ushort_t* __restrict__ qb,
        u8* __restrict__ q8,
        float coef, int do_q, int wq) {
    __shared__ __align__(16) u8 lA[2][256 * 64];   // 32 KB
    __shared__ __align__(16) u8 lB[2][128 * 64];   // 16 KB

    const int tid = threadIdx.x;
    const int lane = tid & 63, wid = tid >> 6;
    const int wd = wid >> 1, wi = wid & 1;     // 4 (d) x 2 (i)
    const int lr = lane & 15, lk = lane >> 4;

    // bijective XCD swizzle, nwg=512; d-half fastest (shares U i-tile in L2)
    int wgid = ((int)blockIdx.x & 7) * 64 + ((int)blockIdx.x >> 3);
    const int  dh = wgid & 1;
    const long a0 = (long)dh * 256;             // d base
    const long b0 = (long)(wgid >> 1) * 128;    // i base

    const int r0  = tid >> 2;                   // 0..127
    const int kc  = tid & 3;
    const int kcs = kc ^ ((r0 >> 1) & 3);
    const u8* gA = W1f8 + (a0 + r0) * (long)H_SZ + kcs * 16;
    const u8* gB = Uf8 + (b0 + r0) * (long)H_SZ + kcs * 16;

#define STG(t) { int _b = (t) & 1; \
    gload_lds16(gA + (long)(t) * 64,               &lA[_b][tid * 16]); \
    gload_lds16(gA + 128L * H_SZ + (long)(t) * 64, &lA[_b][(tid + 512) * 16]); \
    gload_lds16(gB + (long)(t) * 64,               &lB[_b][tid * 16]); }

    f32x4 acc[4][4];
    #pragma unroll
    for (int m = 0; m < 4; ++m)
        #pragma unroll
        for (int n = 0; n < 4; ++n)
            acc[m][n] = (f32x4){0.f, 0.f, 0.f, 0.f};

    const int key = (lr >> 1) & 3;

    STG(0);
    const int NT = H_SZ / 64;   // 32
    for (int t = 0; t < NT; ++t) {
        if (t + 1 < NT) {
            STG(t + 1);
            asm volatile("s_waitcnt vmcnt(3)" ::: "memory");
        } else {
            asm volatile("s_waitcnt vmcnt(0)" ::: "memory");
        }
        __builtin_amdgcn_s_barrier();

        const u8* bA = &lA[t & 1][0];
        const u8* bB = &lB[t & 1][0];
        #pragma unroll
        for (int x = 0; x < 2; ++x) {
            // 8B fragment, k32-subtile x: slot c = x*2 + (lk>>1), XOR key
            const int so = (((x * 2 + (lk >> 1)) ^ key) * 16) + (lk & 1) * 8;
            i64 a[4], b[4];
            #pragma unroll
            for (int m = 0; m < 4; ++m)
                a[m] = *(const i64*)&bA[(wd * 64 + m * 16 + lr) * 64 + so];
            #pragma unroll
            for (int n = 0; n < 4; ++n)
                b[n] = *(const i64*)&bB[(wi * 64 + n * 16 + lr) * 64 + so];
            asm volatile("s_waitcnt lgkmcnt(0)" ::: "memory");
            __builtin_amdgcn_sched_barrier(0);
            __builtin_amdgcn_s_setprio(1);
            #pragma unroll
            for (int m = 0; m < 4; ++m)
                #pragma unroll
                for (int n = 0; n < 4; ++n)
                    acc[m][n] = __builtin_amdgcn_mfma_f32_16x16x32_fp8_fp8(a[m], b[n], acc[m][n], 0, 0, 0);
            __builtin_amdgcn_s_setprio(0);
        }
        __builtin_amdgcn_s_barrier();
    }
#undef STG

    // epilogue: p -= (coef/128)*mask*G ; q = qb + 0.1*p/m*mask -> qb,q8 (+ f32 at wq)
    const float cs = coef * (1.0f / 128.0f);
    #pragma unroll
    for (int n = 0; n < 4; ++n) {
        long i = b0 + wi * 64 + n * 16 + lr;
        int id = ids[i];
        float cm = (id != 0) ? cs : 0.f;
        float hm = (id != 0) ? H_STEP : 0.f;
        float im = inv_mass[(int)(i & (S_SZ - 1))];
        #pragma unroll
        for (int m = 0; m < 4; ++m) {
            long d0 = a0 + wd * 64 + m * 16 + lk * 4;
            size_t off = (size_t)i * D_SZ + d0;
            f32x4 pv = *(const f32x4*)(p + off);
            #pragma unroll
            for (int j = 0; j < 4; ++j)
                pv[j] -= cm * acc[m][n][j];
            *(f32x4*)(p + off) = pv;
            if (do_q) {
                u16x4 qo = *(const u16x4*)(qb + off);
                f32x4 qv;
                u16x4 qn;
                #pragma unroll
                for (int j = 0; j < 4; ++j) {
                    qv[j] = b2f(qo[j]) + hm * pv[j] * im;
                    qn[j] = f2b(qv[j]);
                }
                *(u16x4*)(qb + off) = qn;
                int pk8 = 0;
                pk8 = __builtin_amdgcn_cvt_pk_fp8_f32(qv[0] * 32.f, qv[1] * 32.f, pk8, false);
                pk8 = __builtin_amdgcn_cvt_pk_fp8_f32(qv[2] * 32.f, qv[3] * 32.f, pk8, true);
                *(int*)(q8 + off) = pk8;
                if (wq) *(f32x4*)(qf + off) = qv;
            }
        }
    }
}

// ---------------- host launch ----------------
extern "C" void kernel_launch(void* const* d_in, const int* in_sizes, int n_in,
                              void* d_out, int out_size, void* d_ws, size_t ws_size,
                              hipStream_t stream) {
    const float* table = (const float*)d_in[0];
    const float* logm  = (const float*)d_in[1];
    const float* W1    = (const float*)d_in[2];
    const float* b1    = (const float*)d_in[3];
    const float* W2    = (const float*)d_in[4];
    // d_in[5] = b2, unused by the force (only shifts the potential value)
    const int*   ids   = (const int*)d_in[6];

    float* qf = (float*)d_out;                      // [BS, D] f32 q (written at j=4)
    float* p  = qf + (size_t)BS_SZ * D_SZ;          // [BS, D] f32 p (master, RMW)

    char* ws = (char*)d_ws;
    size_t o = 0;
    ushort_t* qb  = (ushort_t*)(ws + o); o += (size_t)BS_SZ * D_SZ * 2;   // 32 MB (bf16 q master)
    u8* q8        = (u8*)(ws + o);       o += (size_t)BS_SZ * D_SZ;       // 16 MB (fp8 q shadow)
    u8* Uf8       = (u8*)(ws + o);       o += (size_t)BS_SZ * H_SZ;       // 64 MB
    u8* W1f8r     = (u8*)(ws + o);       o += (size_t)H_SZ * D_SZ;        // 1 MB (row-major)
    u8* W1f8      = (u8*)(ws + o);       o += (size_t)D_SZ * H_SZ;        // 1 MB (transposed)
    float* inv_mass = (float*)(ws + o);  o += S_SZ * 4;
    float* mass     = (float*)(ws + o);  o += S_SZ * 4;

    prep_w1r8<<<(H_SZ * D_SZ) / 1024, 256, 0, stream>>>(W1, W1f8r);
    prep_w1t8<<<256, 256, 0, stream>>>(W1, W1f8);
    prep_mass<<<(S_SZ + 255) / 256, 256, 0, stream>>>(logm, inv_mass, mass);
    embed_kernel<<<BS_SZ, 128, 0, stream>>>(table, ids, mass, p, qb, q8);

    // 6 distinct force evals: j=0 -> +0.05*f(q0); j=1..4 -> +0.1*f(qj); j=5 -> +0.05*f(q5)
    for (int j = 0; j < 6; ++j) {
        gemm_f1<<<1024, 1024, 0, stream>>>(W1f8r, q8, b1, W2, Uf8);
        float coef = (j == 0 || j == 5) ? 0.05f : 0.1f;
        gemm_f2<<<512, 512, 0, stream>>>(
            W1f8, Uf8, ids, inv_mass, qf, p, qb, q8, coef, (j < 5) ? 1 : 0, (j == 4) ? 1 : 0);
    }
}

// Round 15
// 1086.986 us; speedup vs baseline: 1.5187x; 1.0052x over previous
//
#include <hip/hip_runtime.h>

// ---------------- problem constants ----------------
#define D_SZ 512
#define S_SZ 1024
#define H_SZ 2048
#define BS_SZ 32768
#define H_STEP 0.1f

typedef __attribute__((ext_vector_type(4))) float f32x4;
typedef __attribute__((ext_vector_type(8))) short s16x8;
typedef __attribute__((ext_vector_type(4))) unsigned short u16x4;
typedef unsigned short ushort_t;
typedef unsigned char u8;
typedef long long i64;

__device__ __forceinline__ ushort_t f2b(float f) {
    unsigned u = __float_as_uint(f);
    unsigned r = (u + 0x7FFFu + ((u >> 16) & 1u)) >> 16;
    return (ushort_t)r;
}
__device__ __forceinline__ float b2f(ushort_t b) {
    return __uint_as_float(((unsigned)b) << 16);
}

__device__ __forceinline__ void gload_lds16(const void* g, void* l) {
    __builtin_amdgcn_global_load_lds(
        (const __attribute__((address_space(1))) unsigned int*)g,
        (__attribute__((address_space(3))) unsigned int*)l, 16, 0, 0);
}

// ---------------- prep kernels ----------------
// W1 row-major fp8 (x8 scale): [2048h][512d]
__global__ void prep_w1r8(const float* __restrict__ W1, u8* __restrict__ W1f8r) {
    int idx4 = (blockIdx.x * 256 + threadIdx.x) * 4;   // over H*D = 1M
    f32x4 v = *(const f32x4*)(W1 + idx4);
    int r = 0;
    r = __builtin_amdgcn_cvt_pk_fp8_f32(v[0] * 8.0f, v[1] * 8.0f, r, false);
    r = __builtin_amdgcn_cvt_pk_fp8_f32(v[2] * 8.0f, v[3] * 8.0f, r, true);
    *(int*)(W1f8r + idx4) = r;
}

// transpose W1 [2048h][512d] -> W1f8 [512d][2048h], fp8 e4m3, x8 scale
__global__ void prep_w1t8(const float* __restrict__ W1, u8* __restrict__ W1f8) {
    __shared__ float t[64][65];
    int hb = blockIdx.x >> 3;      // 0..31
    int db = blockIdx.x & 7;       // 0..7
    int tr = threadIdx.x >> 2;     // 0..63
    int tc = threadIdx.x & 3;      // 0..3
    const float* src = W1 + (size_t)(hb * 64 + tr) * D_SZ + db * 64 + tc * 16;
    #pragma unroll
    for (int j = 0; j < 16; j += 4) {
        f32x4 v = *(const f32x4*)(src + j);
        t[tr][tc * 16 + j + 0] = v[0];
        t[tr][tc * 16 + j + 1] = v[1];
        t[tr][tc * 16 + j + 2] = v[2];
        t[tr][tc * 16 + j + 3] = v[3];
    }
    __syncthreads();
    u8* dst = W1f8 + (size_t)(db * 64 + tr) * H_SZ + hb * 64 + tc * 16;
    #pragma unroll
    for (int j = 0; j < 16; j += 4) {
        int r = 0;
        r = __builtin_amdgcn_cvt_pk_fp8_f32(t[tc * 16 + j + 0][tr] * 8.0f,
                                            t[tc * 16 + j + 1][tr] * 8.0f, r, false);
        r = __builtin_amdgcn_cvt_pk_fp8_f32(t[tc * 16 + j + 2][tr] * 8.0f,
                                            t[tc * 16 + j + 3][tr] * 8.0f, r, true);
        *(int*)(dst + j) = r;
    }
}

__global__ void prep_mass(const float* __restrict__ logm,
                          float* __restrict__ inv_mass,
                          float* __restrict__ mass) {
    int s = blockIdx.x * 256 + threadIdx.x;
    if (s < S_SZ) {
        float lm = logm[s];
        mass[s] = expf(lm);
        inv_mass[s] = expf(-lm);
    }
}

// ---------------- coalesced qb(bf16) -> q8(fp8 x32) conversion ----------------
// 8 elems/thread: 16B read, 8B write, fully coalesced.
__global__ void q8cvt(const ushort_t* __restrict__ qb, u8* __restrict__ q8) {
    size_t idx8 = ((size_t)blockIdx.x * 256 + threadIdx.x) * 8;   // over BS*D
    s16x8 v = *(const s16x8*)(qb + idx8);
    int lo = 0, hi = 0;
    lo = __builtin_amdgcn_cvt_pk_fp8_f32(b2f((ushort_t)v[0]) * 32.f,
                                         b2f((ushort_t)v[1]) * 32.f, lo, false);
    lo = __builtin_amdgcn_cvt_pk_fp8_f32(b2f((ushort_t)v[2]) * 32.f,
                                         b2f((ushort_t)v[3]) * 32.f, lo, true);
    hi = __builtin_amdgcn_cvt_pk_fp8_f32(b2f((ushort_t)v[4]) * 32.f,
                                         b2f((ushort_t)v[5]) * 32.f, hi, false);
    hi = __builtin_amdgcn_cvt_pk_fp8_f32(b2f((ushort_t)v[6]) * 32.f,
                                         b2f((ushort_t)v[7]) * 32.f, hi, true);
    int2 r; r.x = lo; r.y = hi;
    *(int2*)(q8 + idx8) = r;
}

// ---------------- embedding + p0 (q: bf16 master qb + fp8 shadow q8) ----------------
__global__ void embed_kernel(const float* __restrict__ table,
                             const int* __restrict__ ids,
                             const float* __restrict__ mass,
                             float* __restrict__ p,
                             ushort_t* __restrict__ qb,
                             u8* __restrict__ q8) {
    int i = blockIdx.x;          // row index in [0, BS)
    int t = threadIdx.x;
    int s = i & (S_SZ - 1);
    int id = ids[i];
    int idp = (s == 0) ? id : ids[i - 1];   // s==0: prev = self -> vel 0
    float mk = (id != 0) ? 1.f : 0.f;
    float ms = mass[s];
    int d0 = t * 4;

    f32x4 cur = {0.f, 0.f, 0.f, 0.f};
    f32x4 prv = {0.f, 0.f, 0.f, 0.f};
    if (id != 0)  cur = *(const f32x4*)(table + (size_t)id  * D_SZ + d0);
    if (idp != 0) prv = *(const f32x4*)(table + (size_t)idp * D_SZ + d0);

    size_t off = (size_t)i * D_SZ + d0;
    u16x4 cb;
    cb[0] = f2b(cur[0]); cb[1] = f2b(cur[1]); cb[2] = f2b(cur[2]); cb[3] = f2b(cur[3]);
    *(u16x4*)(qb + off) = cb;
    int pk8 = 0;
    pk8 = __builtin_amdgcn_cvt_pk_fp8_f32(cur[0] * 32.f, cur[1] * 32.f, pk8, false);
    pk8 = __builtin_amdgcn_cvt_pk_fp8_f32(cur[2] * 32.f, cur[3] * 32.f, pk8, true);
    *(int*)(q8 + off) = pk8;

    f32x4 pv;
    pv[0] = ms * (cur[0] - prv[0]) * mk;
    pv[1] = ms * (cur[1] - prv[1]) * mk;
    pv[2] = ms * (cur[2] - prv[2]) * mk;
    pv[3] = ms * (cur[3] - prv[3]) * mk;
    *(f32x4*)(p + off) = pv;
}

// =====================================================================
// force1 v4 (fp8 x fp8): 256x256 tile, 1024 threads = 16 waves (4h x 4i),
// wave tile 64x64, acc[4][4]. K=512, BK=64 (8 tiles), 3 LDS bufs (96 KB),
// 2-ahead counted vmcnt(2), T2 XOR-swizzle (16B slots), setprio, XCD swz.
// A = W1f8r (x8) rows h; B = q8 (x32) rows i -> acc = 256*u.
// Epilogue: U[i,h] = fp8_e4m3(16 * sech2(u) * w2[h]).
// =====================================================================
__global__ __launch_bounds__(1024, 4) void gemm_f1(
        const u8* __restrict__ A,      // W1f8r [2048, 512]
        const u8* __restrict__ B,      // q8    [BS, 512]
        const float* __restrict__ b1,
        const float* __restrict__ W2,
        u8* __restrict__ U) {
    constexpr int KLEN = 512;
    constexpr int NT = KLEN / 64;           // 8
    __shared__ __align__(16) u8 lA[3][256 * 64];   // 48 KB
    __shared__ __align__(16) u8 lB[3][256 * 64];   // 48 KB

    const int tid = threadIdx.x;
    const int lane = tid & 63, wid = tid >> 6;
    const int wg = wid >> 2, wn = wid & 3;  // 4 (h) x 4 (i) wave grid
    const int lr = lane & 15, lk = lane >> 4;

    int wgid = ((int)blockIdx.x & 7) * 128 + ((int)blockIdx.x >> 3);  // nwg=1024
    int bxA = wgid & 7;          // 8 h-blocks
    int by  = wgid >> 3;         // 128 i-blocks
    const long a0 = (long)bxA * 256;
    const long b0 = (long)by * 256;

    // staging: 1 16B-chunk per thread per array; row r0 = tid>>2 (0..255),
    // 16B-slot kc = tid&3 of the 64B row-chunk; source slot kcs = kc^((r0>>1)&3)
    const int r0  = tid >> 2;
    const int kc  = tid & 3;
    const int kcs = kc ^ ((r0 >> 1) & 3);
    const u8* gA = A + (a0 + r0) * (long)KLEN + kcs * 16;
    const u8* gB = B + (b0 + r0) * (long)KLEN + kcs * 16;

#define STAGE(t) { int _b = (t) % 3;                           \
    gload_lds16(gA + (long)(t) * 64, &lA[_b][tid * 16]);       \
    gload_lds16(gB + (long)(t) * 64, &lB[_b][tid * 16]); }

    f32x4 acc[4][4];
    #pragma unroll
    for (int m = 0; m < 4; ++m)
        #pragma unroll
        for (int n = 0; n < 4; ++n)
            acc[m][n] = (f32x4){0.f, 0.f, 0.f, 0.f};

    const int key = (lr >> 1) & 3;

    STAGE(0);
    STAGE(1);

    for (int t = 0; t < NT; ++t) {
        const int buf = t % 3;
        const u8* bA = &lA[buf][0];
        const u8* bB = &lB[buf][0];
        if (t < NT - 1) asm volatile("s_waitcnt vmcnt(2)" ::: "memory");
        else           asm volatile("s_waitcnt vmcnt(0)" ::: "memory");
        __builtin_amdgcn_s_barrier();

        #pragma unroll
        for (int x = 0; x < 2; ++x) {
            // 8B fragment, k32-subtile x: 16B-slot c = x*2 + (lk>>1), XOR key
            const int so = (((x * 2 + (lk >> 1)) ^ key) * 16) + (lk & 1) * 8;
            i64 a[4], b[4];
            #pragma unroll
            for (int m = 0; m < 4; ++m)
                a[m] = *(const i64*)&bA[(wg * 64 + m * 16 + lr) * 64 + so];
            #pragma unroll
            for (int n = 0; n < 4; ++n)
                b[n] = *(const i64*)&bB[(wn * 64 + n * 16 + lr) * 64 + so];
            asm volatile("s_waitcnt lgkmcnt(0)" ::: "memory");
            __builtin_amdgcn_sched_barrier(0);
            __builtin_amdgcn_s_setprio(1);
            #pragma unroll
            for (int m = 0; m < 4; ++m)
                #pragma unroll
                for (int n = 0; n < 4; ++n)
                    acc[m][n] = __builtin_amdgcn_mfma_f32_16x16x32_fp8_fp8(a[m], b[n], acc[m][n], 0, 0, 0);
            __builtin_amdgcn_s_setprio(0);
        }
        __builtin_amdgcn_s_barrier();
        if (t + 2 < NT) STAGE(t + 2);
    }
#undef STAGE

    // epilogue: u = acc/256; U[i,h] = fp8(16*sech2(u)*w2)
    #pragma unroll
    for (int m = 0; m < 4; ++m) {
        long h0 = a0 + wg * 64 + m * 16 + lk * 4;
        f32x4 b1v = *(const f32x4*)(b1 + h0);
        f32x4 w2v = *(const f32x4*)(W2 + h0);
        #pragma unroll
        for (int n = 0; n < 4; ++n) {
            long i = b0 + wn * 64 + n * 16 + lr;
            float v[4];
            #pragma unroll
            for (int j = 0; j < 4; ++j) {
                float uu = acc[m][n][j] * 0.00390625f + b1v[j];
                // 16*sech^2(u)*w2 = 64*e/(1+e)^2*w2, e = exp(-2|u|)
                float e = __expf(-2.0f * fabsf(uu));
                float rc = 1.0f / (1.0f + e);
                v[j] = 64.0f * e * rc * rc * w2v[j];
            }
            int pk = 0;
            pk = __builtin_amdgcn_cvt_pk_fp8_f32(v[0], v[1], pk, false);
            pk = __builtin_amdgcn_cvt_pk_fp8_f32(v[2], v[3], pk, true);
            *(int*)(U + i * H_SZ + h0) = pk;
        }
    }
}

// =====================================================================
// force2 (fp8 x fp8): grid 512 = 2 d-halves x 256 i-tiles.
// Block = 256d x 128i, K=2048, BK=64. 8 waves = 4(d) x 2(i), 64d x 64i.
// Counted vmcnt(3). Epilogue (R12-measured form, NO q8 store):
//   p(f32,RMW) -= (coef/128)*mask*G
//   if do_q: q = b2f(qb) + 0.1*p/m*mask -> qb (bf16); if wq also q f32 out.
// =====================================================================
__global__ __launch_bounds__(512, 2) void gemm_f2(
        const u8* __restrict__ W1f8,   // [512][2048]
        const u8* __restrict__ Uf8,    // [BS][2048]
        const int* __restrict__ ids,
        const float* __restrict__ inv_mass,
        float* __restrict__ qf,        // f32 q output (d_out), written when wq
        float* __restrict__ p,
        ushort_t* __restrict__ qb,
        float coef, int do_q, int wq) {
    __shared__ __align__(16) u8 lA[2][256 * 64];   // 32 KB
    __shared__ __align__(16) u8 lB[2][128 * 64];   // 16 KB

    const int tid = threadIdx.x;
    const int lane = tid & 63, wid = tid >> 6;
    const int wd = wid >> 1, wi = wid & 1;     // 4 (d) x 2 (i)
    const int lr = lane & 15, lk = lane >> 4;

    // bijective XCD swizzle, nwg=512; d-half fastest (shares U i-tile in L2)
    int wgid = ((int)blockIdx.x & 7) * 64 + ((int)blockIdx.x >> 3);
    const int  dh = wgid & 1;
    const long a0 = (long)dh * 256;             // d base
    const long b0 = (long)(wgid >> 1) * 128;    // i base

    const int r0  = tid >> 2;                   // 0..127
    const int kc  = tid & 3;
    const int kcs = kc ^ ((r0 >> 1) & 3);
    const u8* gA = W1f8 + (a0 + r0) * (long)H_SZ + kcs * 16;
    const u8* gB = Uf8 + (b0 + r0) * (long)H_SZ + kcs * 16;

#define STG(t) { int _b = (t) & 1; \
    gload_lds16(gA + (long)(t) * 64,               &lA[_b][tid * 16]); \
    gload_lds16(gA + 128L * H_SZ + (long)(t) * 64, &lA[_b][(tid + 512) * 16]); \
    gload_lds16(gB + (long)(t) * 64,               &lB[_b][tid * 16]); }

    f32x4 acc[4][4];
    #pragma unroll
    for (int m = 0; m < 4; ++m)
        #pragma unroll
        for (int n = 0; n < 4; ++n)
            acc[m][n] = (f32x4){0.f, 0.f, 0.f, 0.f};

    const int key = (lr >> 1) & 3;

    STG(0);
    const int NT = H_SZ / 64;   // 32
    for (int t = 0; t < NT; ++t) {
        if (t + 1 < NT) {
            STG(t + 1);
            asm volatile("s_waitcnt vmcnt(3)" ::: "memory");
        } else {
            asm volatile("s_waitcnt vmcnt(0)" ::: "memory");
        }
        __builtin_amdgcn_s_barrier();

        const u8* bA = &lA[t & 1][0];
        const u8* bB = &lB[t & 1][0];
        #pragma unroll
        for (int x = 0; x < 2; ++x) {
            // 8B fragment, k32-subtile x: slot c = x*2 + (lk>>1), XOR key
            const int so = (((x * 2 + (lk >> 1)) ^ key) * 16) + (lk & 1) * 8;
            i64 a[4], b[4];
            #pragma unroll
            for (int m = 0; m < 4; ++m)
                a[m] = *(const i64*)&bA[(wd * 64 + m * 16 + lr) * 64 + so];
            #pragma unroll
            for (int n = 0; n < 4; ++n)
                b[n] = *(const i64*)&bB[(wi * 64 + n * 16 + lr) * 64 + so];
            asm volatile("s_waitcnt lgkmcnt(0)" ::: "memory");
            __builtin_amdgcn_sched_barrier(0);
            __builtin_amdgcn_s_setprio(1);
            #pragma unroll
            for (int m = 0; m < 4; ++m)
                #pragma unroll
                for (int n = 0; n < 4; ++n)
                    acc[m][n] = __builtin_amdgcn_mfma_f32_16x16x32_fp8_fp8(a[m], b[n], acc[m][n], 0, 0, 0);
            __builtin_amdgcn_s_setprio(0);
        }
        __builtin_amdgcn_s_barrier();
    }
#undef STG

    // epilogue: p -= (coef/128)*mask*G ; q = qb + 0.1*p/m*mask -> qb (+ f32 at wq)
    const float cs = coef * (1.0f / 128.0f);
    #pragma unroll
    for (int n = 0; n < 4; ++n) {
        long i = b0 + wi * 64 + n * 16 + lr;
        int id = ids[i];
        float cm = (id != 0) ? cs : 0.f;
        float hm = (id != 0) ? H_STEP : 0.f;
        float im = inv_mass[(int)(i & (S_SZ - 1))];
        #pragma unroll
        for (int m = 0; m < 4; ++m) {
            long d0 = a0 + wd * 64 + m * 16 + lk * 4;
            size_t off = (size_t)i * D_SZ + d0;
            f32x4 pv = *(const f32x4*)(p + off);
            #pragma unroll
            for (int j = 0; j < 4; ++j)
                pv[j] -= cm * acc[m][n][j];
            *(f32x4*)(p + off) = pv;
            if (do_q) {
                u16x4 qo = *(const u16x4*)(qb + off);
                f32x4 qv;
                u16x4 qn;
                #pragma unroll
                for (int j = 0; j < 4; ++j) {
                    qv[j] = b2f(qo[j]) + hm * pv[j] * im;
                    qn[j] = f2b(qv[j]);
                }
                *(u16x4*)(qb + off) = qn;
                if (wq) *(f32x4*)(qf + off) = qv;
            }
        }
    }
}

// ---------------- host launch ----------------
extern "C" void kernel_launch(void* const* d_in, const int* in_sizes, int n_in,
                              void* d_out, int out_size, void* d_ws, size_t ws_size,
                              hipStream_t stream) {
    const float* table = (const float*)d_in[0];
    const float* logm  = (const float*)d_in[1];
    const float* W1    = (const float*)d_in[2];
    const float* b1    = (const float*)d_in[3];
    const float* W2    = (const float*)d_in[4];
    // d_in[5] = b2, unused by the force (only shifts the potential value)
    const int*   ids   = (const int*)d_in[6];

    float* qf = (float*)d_out;                      // [BS, D] f32 q (written at j=4)
    float* p  = qf + (size_t)BS_SZ * D_SZ;          // [BS, D] f32 p (master, RMW)

    char* ws = (char*)d_ws;
    size_t o = 0;
    ushort_t* qb  = (ushort_t*)(ws + o); o += (size_t)BS_SZ * D_SZ * 2;   // 32 MB (bf16 q master)
    u8* q8        = (u8*)(ws + o);       o += (size_t)BS_SZ * D_SZ;       // 16 MB (fp8 q shadow)
    u8* Uf8       = (u8*)(ws + o);       o += (size_t)BS_SZ * H_SZ;       // 64 MB
    u8* W1f8r     = (u8*)(ws + o);       o += (size_t)H_SZ * D_SZ;        // 1 MB (row-major)
    u8* W1f8      = (u8*)(ws + o);       o += (size_t)D_SZ * H_SZ;        // 1 MB (transposed)
    float* inv_mass = (float*)(ws + o);  o += S_SZ * 4;
    float* mass     = (float*)(ws + o);  o += S_SZ * 4;

    prep_w1r8<<<(H_SZ * D_SZ) / 1024, 256, 0, stream>>>(W1, W1f8r);
    prep_w1t8<<<256, 256, 0, stream>>>(W1, W1f8);
    prep_mass<<<(S_SZ + 255) / 256, 256, 0, stream>>>(logm, inv_mass, mass);
    embed_kernel<<<BS_SZ, 128, 0, stream>>>(table, ids, mass, p, qb, q8);

    // 6 distinct force evals: j=0 -> +0.05*f(q0); j=1..4 -> +0.1*f(qj); j=5 -> +0.05*f(q5)
    for (int j = 0; j < 6; ++j) {
        gemm_f1<<<1024, 1024, 0, stream>>>(W1f8r, q8, b1, W2, Uf8);
        float coef = (j == 0 || j == 5) ? 0.05f : 0.1f;
        gemm_f2<<<512, 512, 0, stream>>>(
            W1f8, Uf8, ids, inv_mass, qf, p, qb, coef, (j < 5) ? 1 : 0, (j == 4) ? 1 : 0);
        if (j < 5)
            q8cvt<<<(BS_SZ * D_SZ) / (256 * 8), 256, 0, stream>>>(qb, q8);
    }
}